// Round 6
// baseline (550.027 us; speedup 1.0000x reference)
//
#include <hip/hip_runtime.h>
#include <hip/hip_bf16.h>

// ROUND 11: pipeline + deswizzle the GEMM. Round 10 counters: gemm ~94us with
// MfmaUtil 10.6 / VALUBusy 23 / Occ 27 / HBM 31% -> latency+barrier-bound
// (loads fully exposed each K-step: load -> barrier -> LDS write -> barrier ->
// compute), plus 3.1M LDS bank conflicts (128x32 u16 tile, 64B row stride ->
// 8-way on column-slice ds_read_b128). This round, gemm only:
//  (1) double-buffered LDS (2x16KB) + 1-tile-ahead register prefetch, loop
//      2x-unrolled so buffer indices are static; one barrier per K-step;
//      loads issued right after the ds_write of the previous tile -> a full
//      iteration of latency cover. K in {384,256} = multiples of 64, no tail.
//  (2) granule XOR swizzle: chunk (row,g) stored at granule g^((row>>1)&3),
//      fragment read at q^((l15>>1)&3) -> write and read both perfectly
//      bank-balanced (bijective within each row).
//  (3) stats staging without LDS atomics: sds[2][128] slots each written by
//      exactly one (wave,lane) -> plain ds_write; no zero pass; stores issued
//      before stats to overlap. Global atomicAdd tail unchanged (passed r10).
// knn (82us, scalarized s_load) and all other kernels: round 10 verbatim.

typedef unsigned int u32;
typedef unsigned short u16;
typedef unsigned long long u64;
typedef __attribute__((ext_vector_type(8))) short short8;   // 8 x bf16 bits
typedef __attribute__((ext_vector_type(4))) float f32x4;

#define NT_TOTAL 131072   // B*N flattened columns
#define NN 16384
#define SS 2048

__device__ __forceinline__ float bf2f(u16 u) {
    union { u32 i; float f; } cv; cv.i = ((u32)u) << 16; return cv.f;
}
__device__ __forceinline__ u16 f2bf(float f) {
    union { float f; u32 i; } cv; cv.f = f;
    const u32 r = (cv.i + 0x7FFFu + ((cv.i >> 16) & 1u)) >> 16;   // RNE
    return (u16)r;
}
// dual-dtype scalar load (isbf wave-uniform)
__device__ __forceinline__ float ldf(const void* p, int i, int isbf) {
    return isbf ? bf2f(((const u16*)p)[i]) : ((const float*)p)[i];
}

// ---------------- detect dtype + zero stats (1 block, 256 thr) -----------------------
__global__ __launch_bounds__(256)
void detect_kernel(const u32* __restrict__ xyz1w, u32* __restrict__ flag,
                   float* __restrict__ stats)
{
    __shared__ int cnt;
    const int t = threadIdx.x;
    if (t == 0) cnt = 0;
    for (int i = t; i < 1024; i += 256) stats[i] = 0.f;
    __syncthreads();
    if (t < 64) {
        const u32 w = xyz1w[t];
        const int e = (int)((w >> 7) & 0xFF);   // bf16 exponent of LOW u16
        if (e >= 96 && e <= 144) atomicAdd(&cnt, 1);
    }
    __syncthreads();
    if (t == 0) flag[0] = (cnt >= 48) ? 1u : 0u;   // p~1 if packed bf16, p~0.19 if fp32
}

// ---------------- sentinel fill (u16 pattern 0x4496 ~ 1200) --------------------------
__global__ __launch_bounds__(256)
void sentinel_kernel(u16* __restrict__ out, int n)
{
    const int i = blockIdx.x * 256 + threadIdx.x;
    if (i < n) out[i] = 0x4496;
}

// ---------------- convert W -> bf16, params -> fp32 ----------------------------------
__global__ __launch_bounds__(256)
void param_kernel(const void* W0, const void* b0, const void* g0, const void* bt0,
                  const void* W1, const void* b1, const void* g1, const void* bt1,
                  const u32* __restrict__ flag,
                  u16* __restrict__ Wb0, u16* __restrict__ Wb1, float* __restrict__ pf)
{
    const int isbf = (int)flag[0];
    const int i = blockIdx.x * 256 + threadIdx.x;   // up to 98304
    if (i < 98304) Wb0[i] = f2bf(ldf(W0, i, isbf));
    if (i < 65536) Wb1[i] = f2bf(ldf(W1, i, isbf));
    if (i < 1536) {
        const void* srcs[6] = { b0, g0, bt0, b1, g1, bt1 };
        pf[i] = ldf(srcs[i >> 8], i & 255, isbf);
    }
}

// ---------------- pack xyz2 -> float4(x,y,z,|s|^2) -----------------------------------
__global__ __launch_bounds__(256)
void pack2_kernel(const void* __restrict__ xyz2, float4* __restrict__ s2q,
                  const u32* __restrict__ flag)
{
    const int isbf = (int)flag[0];
    const int i = blockIdx.x * 256 + threadIdx.x;   // 8*2048 points
    if (i < 8 * SS) {
        const float x = ldf(xyz2, i * 3 + 0, isbf);
        const float y = ldf(xyz2, i * 3 + 1, isbf);
        const float z = ldf(xyz2, i * 3 + 2, isbf);
        float4 v; v.x = x; v.y = y; v.z = z; v.w = x * x + y * y + z * z;
        s2q[i] = v;
    }
}

// ---------------- transpose (bz,Cc,Np) -> bf16 out[(bz*Np+n)*ldout+coff+c] -----------
__global__ __launch_bounds__(256)
void transpose_kernel(const void* __restrict__ in, u16* __restrict__ out,
                      int Cc, int Np, int ldout, int coff, const u32* __restrict__ flag)
{
    __shared__ u16 tile[64][72];
    const int isbf = (int)flag[0];
    const int t = threadIdx.x;
    const int n0 = blockIdx.x * 64, c0 = blockIdx.y * 64, bz = blockIdx.z;
    const int ch = t & 7, r = t >> 3;     // r: 0..31
#pragma unroll
    for (int p = 0; p < 2; ++p) {
        const int cl = r + p * 32;
        const size_t idx = ((size_t)(bz * Cc + c0 + cl)) * Np + n0 + ch * 8;
        union { uint4 v; u16 us[8]; } pk;
        if (isbf) {
            pk.v = *(const uint4*)((const u16*)in + idx);
        } else {
            const float4 va = *(const float4*)((const float*)in + idx);
            const float4 vb = *(const float4*)((const float*)in + idx + 4);
            pk.us[0] = f2bf(va.x); pk.us[1] = f2bf(va.y);
            pk.us[2] = f2bf(va.z); pk.us[3] = f2bf(va.w);
            pk.us[4] = f2bf(vb.x); pk.us[5] = f2bf(vb.y);
            pk.us[6] = f2bf(vb.z); pk.us[7] = f2bf(vb.w);
        }
        *(uint4*)&tile[cl][ch * 8] = pk.v;
    }
    __syncthreads();
#pragma unroll
    for (int p = 0; p < 2; ++p) {
        const int nl = r + p * 32;
        union { uint4 v; u16 us[8]; } pk;
#pragma unroll
        for (int i = 0; i < 8; ++i) pk.us[i] = tile[ch * 8 + i][nl];
        *(uint4*)&out[((size_t)(bz * Np + n0 + nl)) * ldout + coff + c0 + ch * 8] = pk.v;
    }
}

// ---------------- knn v5: 4-wave split + FORCED-uniform s_load + exact refine --------
__global__ __launch_bounds__(256)
void knn_kernel(const float4* __restrict__ s2q, const void* __restrict__ xyz1,
                u32* __restrict__ idxA, float* __restrict__ wA,
                const u32* __restrict__ flag)
{
    __shared__ float skeys[4][64][5];
    const int isbf = (int)flag[0];
    const int t = threadIdx.x;
    const int lane = t & 63;
    const int wid = __builtin_amdgcn_readfirstlane(t >> 6);   // provably uniform
    const int qg = blockIdx.x * 64 + lane;         // 64 queries per block
    const int b = blockIdx.x >> 8;                 // 256 blocks per batch
    const float qx = ldf(xyz1, qg * 3 + 0, isbf);
    const float qy = ldf(xyz1, qg * 3 + 1, isbf);
    const float qz = ldf(xyz1, qg * 3 + 2, isbf);
    const float qx2 = -2.f * qx, qy2 = -2.f * qy, qz2 = -2.f * qz;
    const float qc = qx * qx + qy * qy + qz * qz;   // |q|^2
    const float4* __restrict__ S = s2q + (size_t)b * SS;

    // sorted top-5 of packed keys: key = (d_bits & ~0x7FF) | s  (fp32 compare)
    float k0 = __builtin_inff(), k1 = k0, k2 = k0, k3 = k0, k4 = k0;
    const int sbase = wid * 512;                    // SGPR
#pragma unroll 8
    for (int it = 0; it < 512; ++it) {
        const int s = sbase + it;
        const float4 v = S[s];                      // uniform -> s_load_dwordx4
        float d = fmaf(v.x, qx2, qc);
        d = fmaf(v.y, qy2, d);
        d = fmaf(v.z, qz2, d);
        d += v.w;                                   // |q|^2 - 2 q.s + |s|^2
        const float k = __uint_as_float((__float_as_uint(d) & 0xFFFFF800u) | (u32)s);
        const float o0 = fminf(k, k0);
        const float o1 = __builtin_amdgcn_fmed3f(k, k0, k1);
        const float o2 = __builtin_amdgcn_fmed3f(k, k1, k2);
        const float o3 = __builtin_amdgcn_fmed3f(k, k2, k3);
        const float o4 = __builtin_amdgcn_fmed3f(k, k3, k4);
        k0 = o0; k1 = o1; k2 = o2; k3 = o3; k4 = o4;
    }
    skeys[wid][lane][0] = k0;
    skeys[wid][lane][1] = k1;
    skeys[wid][lane][2] = k2;
    skeys[wid][lane][3] = k3;
    skeys[wid][lane][4] = k4;
    __syncthreads();
    if (wid != 0) return;

    // exact refine: recompute subtract-form distances for the 20 survivors,
    // select top-3 on u64 key (d_bits<<11 | idx) -> exact values + tie->low idx
    u64 e0 = ~0ull, e1 = ~0ull, e2 = ~0ull;
#pragma unroll
    for (int w = 0; w < 4; ++w)
#pragma unroll
        for (int i = 0; i < 5; ++i) {
            const u32 idx = __float_as_uint(skeys[w][lane][i]) & 0x7FFu;
            const float4 c = S[idx];                 // per-lane gather (L1/L2 hit)
            const float dx = qx - c.x, dy = qy - c.y, dz = qz - c.z;
            const float d = fmaf(dz, dz, fmaf(dy, dy, dx * dx));   // exact, >= 0
            const u64 e = ((u64)__float_as_uint(d) << 11) | (u64)idx;
            const bool c0 = e < e0, c1 = e < e1, c2 = e < e2;
            e2 = c1 ? e1 : (c2 ? e : e2);
            e1 = c0 ? e0 : (c1 ? e : e1);
            e0 = c0 ? e : e0;
        }
    const u32 i0 = (u32)(e0 & 0x7FF), i1 = (u32)(e1 & 0x7FF), i2 = (u32)(e2 & 0x7FF);
    const float d0 = fmaxf(__uint_as_float((u32)(e0 >> 11)), 1e-10f);
    const float d1 = fmaxf(__uint_as_float((u32)(e1 >> 11)), 1e-10f);
    const float d2 = fmaxf(__uint_as_float((u32)(e2 >> 11)), 1e-10f);
    const float w0 = 1.f / d0, w1 = 1.f / d1, w2 = 1.f / d2;
    const float inv = 1.f / (w0 + w1 + w2);
    idxA[qg * 3 + 0] = i0; idxA[qg * 3 + 1] = i1; idxA[qg * 3 + 2] = i2;
    wA[qg * 3 + 0] = w0 * inv; wA[qg * 3 + 1] = w1 * inv; wA[qg * 3 + 2] = w2 * inv;
}

// ---------------- interp: hT[n][0..255] = sum_k w_k * p2T[b][idx_k][c] (bf16) --------
__global__ __launch_bounds__(256)
void interp_kernel(const u16* __restrict__ p2T, const u32* __restrict__ idxA,
                   const float* __restrict__ wA, u16* __restrict__ hT)
{
    const int t = threadIdx.x;
    const int pl = t >> 5, g = t & 31;           // 8 points/block, 32 lanes/point
    const int qg = blockIdx.x * 8 + pl;
    const int b = qg >> 14;
    float acc[8] = {0.f, 0.f, 0.f, 0.f, 0.f, 0.f, 0.f, 0.f};
#pragma unroll
    for (int k = 0; k < 3; ++k) {
        const u32 idx = idxA[qg * 3 + k];
        const float w = wA[qg * 3 + k];
        union { uint4 v; u16 us[8]; } pk;
        pk.v = *(const uint4*)(p2T + ((size_t)(b * SS + idx)) * 256 + g * 8);
#pragma unroll
        for (int e = 0; e < 8; ++e) acc[e] = fmaf(w, bf2f(pk.us[e]), acc[e]);
    }
    union { uint4 v; u16 us[8]; } ov;
#pragma unroll
    for (int e = 0; e < 8; ++e) ov.us[e] = f2bf(acc[e]);
    *(uint4*)&hT[(size_t)qg * 384 + g * 8] = ov.v;
}

// ---------------- GEMM (pipelined, swizzled) + fused BN-stats ------------------------
// y[(b,m,n)] = sum_k A[m][k]*B[col][k] + bias[m]; per-channel sum/sumsq of v
// accumulated into sums/sumsq. Double-buffered LDS, 1-tile-ahead reg prefetch,
// granule XOR swizzle (store g^((row>>1)&3), read q^((l15>>1)&3)).
#define GEMM_BODY(BUF, OTH, KCUR)                                                        \
    {                                                                                    \
        short8 a[4], b[4];                                                               \
        _Pragma("unroll")                                                                \
        for (int i = 0; i < 4; ++i) a[i] = *(const short8*)&aT[BUF][aoff[i]];            \
        _Pragma("unroll")                                                                \
        for (int j = 0; j < 4; ++j) b[j] = *(const short8*)&bT[BUF][boff[j]];            \
        _Pragma("unroll")                                                                \
        for (int i = 0; i < 4; ++i)                                                      \
            _Pragma("unroll")                                                            \
            for (int j = 0; j < 4; ++j)                                                  \
                acc[i][j] = __builtin_amdgcn_mfma_f32_16x16x32_bf16(a[i], b[j], acc[i][j], 0, 0, 0); \
        if ((KCUR) + 32 < K) {                                                           \
            *(uint4*)&aT[OTH][o0] = ra0; *(uint4*)&aT[OTH][o1] = ra1;                    \
            *(uint4*)&bT[OTH][o0] = rb0; *(uint4*)&bT[OTH][o1] = rb1;                    \
            if ((KCUR) + 64 < K) {                                                       \
                ra0 = *(const uint4*)(gA0 + (KCUR) + 64);                                \
                ra1 = *(const uint4*)(gA1 + (KCUR) + 64);                                \
                rb0 = *(const uint4*)(gB0 + (KCUR) + 64);                                \
                rb1 = *(const uint4*)(gB1 + (KCUR) + 64);                                \
            }                                                                            \
        }                                                                                \
        __syncthreads();                                                                 \
    }

__global__ __launch_bounds__(256)
void gemm_kernel(const u16* __restrict__ A, const u16* __restrict__ Bm,
                 const float* __restrict__ bias, void* __restrict__ yout, int K,
                 const u32* __restrict__ flag,
                 float* __restrict__ sums, float* __restrict__ sumsq)
{
    __shared__ __align__(16) u16 aT[2][128 * 32];
    __shared__ __align__(16) u16 bT[2][128 * 32];
    const int isbf = (int)flag[0];
    const int t = threadIdx.x;
    const int lane = t & 63;
    const int l15 = lane & 15;
    const int q = lane >> 4;
    const int wid = t >> 6;
    const int n0 = blockIdx.x * 128;
    const int m0 = blockIdx.y * 128;
    const int wm = (wid & 1) * 64;
    const int wn = (wid >> 1) * 64;

    f32x4 acc[4][4] = {};

    // staging chunks: ca0=t (rows 0..63), ca1=t+256 (rows 64..127); granule swizzle
    const int ca0 = t, ca1 = t + 256;
    const u16* gA0 = A + (size_t)(m0 + (ca0 >> 2)) * K + (ca0 & 3) * 8;
    const u16* gA1 = A + (size_t)(m0 + (ca1 >> 2)) * K + (ca1 & 3) * 8;
    const u16* gB0 = Bm + (size_t)(n0 + (ca0 >> 2)) * K + (ca0 & 3) * 8;
    const u16* gB1 = Bm + (size_t)(n0 + (ca1 >> 2)) * K + (ca1 & 3) * 8;
    const int o0 = (ca0 >> 2) * 32 + (((ca0 & 3) ^ ((ca0 >> 3) & 3)) * 8);
    const int o1 = (ca1 >> 2) * 32 + (((ca1 & 3) ^ ((ca1 >> 3) & 3)) * 8);

    // fragment read offsets (logical granule q lives at physical q^gsw)
    const int gsw = (l15 >> 1) & 3;
    int aoff[4], boff[4];
#pragma unroll
    for (int i = 0; i < 4; ++i) {
        aoff[i] = (wm + i * 16 + l15) * 32 + ((q ^ gsw) * 8);
        boff[i] = (wn + i * 16 + l15) * 32 + ((q ^ gsw) * 8);
    }

    // prologue: tile 0 -> buf0; prefetch tile 1 into regs
    uint4 ra0 = *(const uint4*)(gA0);
    uint4 ra1 = *(const uint4*)(gA1);
    uint4 rb0 = *(const uint4*)(gB0);
    uint4 rb1 = *(const uint4*)(gB1);
    *(uint4*)&aT[0][o0] = ra0; *(uint4*)&aT[0][o1] = ra1;
    *(uint4*)&bT[0][o0] = rb0; *(uint4*)&bT[0][o1] = rb1;
    ra0 = *(const uint4*)(gA0 + 32);
    ra1 = *(const uint4*)(gA1 + 32);
    rb0 = *(const uint4*)(gB0 + 32);
    rb1 = *(const uint4*)(gB1 + 32);
    __syncthreads();

    for (int kk = 0; kk < K; kk += 64) {
        GEMM_BODY(0, 1, kk)
        GEMM_BODY(1, 0, kk + 32)
    }

    // ---- store epilogue first (no LDS; overlaps with stats below) ----
#pragma unroll
    for (int i = 0; i < 4; ++i) {
        const int mBase = m0 + wm + i * 16 + q * 4;   // D row = q*4+reg
        float bi[4];
#pragma unroll
        for (int r = 0; r < 4; ++r) bi[r] = bias[mBase + r];
#pragma unroll
        for (int j = 0; j < 4; ++j) {
            const int col = n0 + wn + j * 16 + l15;    // D col = lane&15
            const size_t obase = ((size_t)(col >> 14) * 256) * NN + (col & 16383);
#pragma unroll
            for (int r = 0; r < 4; ++r) {
                const float v = acc[i][j][r] + bi[r];
                const size_t oi = obase + (size_t)(mBase + r) * NN;
                if (isbf) ((u16*)yout)[oi] = f2bf(v);
                else      ((float*)yout)[oi] = v;
            }
        }
    }

    // ---- fused per-channel stats (no LDS atomics: one writer per slot) ----
    // sds layout: [0..255] = sum slots (wp*128+c), [256..511] = sumsq slots
    float* sds = (float*)&aT[0][0];
    const int wp = wid >> 1;
#pragma unroll
    for (int i = 0; i < 4; ++i) {
        const int mloc = wm + i * 16 + q * 4;     // channel - m0
#pragma unroll
        for (int r = 0; r < 4; ++r) {
            const float bi = bias[m0 + mloc + r];
            float s = 0.f, sq = 0.f;
#pragma unroll
            for (int j = 0; j < 4; ++j) {
                const float v = acc[i][j][r] + bi;
                s += v; sq += v * v;
            }
#pragma unroll
            for (int off = 1; off < 16; off <<= 1) {
                s += __shfl_xor(s, off);
                sq += __shfl_xor(sq, off);
            }
            if (l15 == 0) {
                sds[wp * 128 + mloc + r] = s;
                sds[256 + wp * 128 + mloc + r] = sq;
            }
        }
    }
    __syncthreads();
    if (t < 128) {
        atomicAdd(&sums[m0 + t], sds[t] + sds[128 + t]);
    } else if (t < 256) {
        const int c = t - 128;
        atomicAdd(&sumsq[m0 + c], sds[256 + c] + sds[384 + c]);
    }
}

// ---------------- BN + ReLU + transpose (y in d_out -> n-major bf16 h2) --------------
__global__ __launch_bounds__(256)
void bn_act_tr_kernel(const void* __restrict__ y, const float* __restrict__ sums,
                      const float* __restrict__ sumsq, const float* __restrict__ gam,
                      const float* __restrict__ beta, u16* __restrict__ h2,
                      const u32* __restrict__ flag)
{
    __shared__ u16 tile[64][68];
    const int isbf = (int)flag[0];
    const int t = threadIdx.x;
    const int n0g = blockIdx.x * 64, c0 = blockIdx.y * 64;
    const int bb = n0g >> 14, nn0 = n0g & 16383;
    const float invNT = 1.0f / (float)NT_TOTAL;
    {
        const int f4 = t & 15, cbase = t >> 4;
#pragma unroll
        for (int p = 0; p < 4; ++p) {
            const int cl = cbase + p * 16;
            const int c = c0 + cl;
            const float mean = sums[c] * invNT;
            const float var = sumsq[c] * invNT - mean * mean;
            const float rstd = rsqrtf(var + 1e-5f);
            const float sc = gam[c] * rstd;
            const float sh = beta[c] - mean * sc;
            const size_t base = ((size_t)(bb * 256 + c)) * NN + nn0 + f4 * 4;
            float in4[4];
            if (isbf) {
                union { uint2 v2; u16 us[4]; } iv;
                iv.v2 = *(const uint2*)((const u16*)y + base);
#pragma unroll
                for (int e = 0; e < 4; ++e) in4[e] = bf2f(iv.us[e]);
            } else {
                const float4 v = *(const float4*)((const float*)y + base);
                in4[0] = v.x; in4[1] = v.y; in4[2] = v.z; in4[3] = v.w;
            }
            union { uint2 v2; u16 us[4]; } o;
#pragma unroll
            for (int e = 0; e < 4; ++e) {
                float v = in4[e] * sc + sh;
                v = (v != v) ? 777.0f : fmaxf(v, 0.f);   // NaN canary
                o.us[e] = f2bf(v);
            }
            *(uint2*)&tile[cl][f4 * 4] = o.v2;
        }
    }
    __syncthreads();
    {
        const int ch = t & 7, rr = t >> 3;
#pragma unroll
        for (int p = 0; p < 2; ++p) {
            const int nl = rr + p * 32;
            union { uint4 v; u16 us[8]; } pk;
#pragma unroll
            for (int i = 0; i < 8; ++i) pk.us[i] = tile[ch * 8 + i][nl];
            *(uint4*)&h2[((size_t)(n0g + nl)) * 256 + c0 + ch * 8] = pk.v;
        }
    }
}

// ---------------- final BN + ReLU, IN-PLACE on d_out ---------------------------------
__global__ __launch_bounds__(256)
void final_kernel(void* __restrict__ y, const float* __restrict__ sums,
                  const float* __restrict__ sumsq, const float* __restrict__ gam,
                  const float* __restrict__ beta, const u32* __restrict__ flag)
{
    const int isbf = (int)flag[0];
    const int gid = blockIdx.x * 256 + threadIdx.x;   // x4 elements
    const int c = (gid >> 12) & 255;
    const float invNT = 1.0f / (float)NT_TOTAL;
    const float mean = sums[c] * invNT;
    const float var = sumsq[c] * invNT - mean * mean;
    const float rstd = rsqrtf(var + 1e-5f);
    const float sc = gam[c] * rstd;
    const float sh = beta[c] - mean * sc;
    const size_t idx4 = (size_t)gid * 4;
    float in4[4];
    if (isbf) {
        union { uint2 v2; u16 us[4]; } iv;
        iv.v2 = *(const uint2*)((const u16*)y + idx4);
#pragma unroll
        for (int e = 0; e < 4; ++e) in4[e] = bf2f(iv.us[e]);
    } else {
        const float4 v = *(const float4*)((const float*)y + idx4);
        in4[0] = v.x; in4[1] = v.y; in4[2] = v.z; in4[3] = v.w;
    }
    float o4[4];
#pragma unroll
    for (int e = 0; e < 4; ++e) {
        float v = in4[e] * sc + sh;
        o4[e] = (v != v) ? 777.0f : fmaxf(v, 0.f);    // NaN canary
    }
    if (isbf) {
        union { uint2 v2; u16 us[4]; } o;
#pragma unroll
        for (int e = 0; e < 4; ++e) o.us[e] = f2bf(o4[e]);
        *(uint2*)((u16*)y + idx4) = o.v2;
    } else {
        float4 o; o.x = o4[0]; o.y = o4[1]; o.z = o4[2]; o.w = o4[3];
        *(float4*)((float*)y + idx4) = o;
    }
}

// kept in case the harness expects this symbol to exist (never launched)
__global__ void pointnet_fp_module_24532853195517_kernel() {}

extern "C" void kernel_launch(void* const* d_in, const int* in_sizes, int n_in,
                              void* d_out, int out_size, void* d_ws, size_t ws_size,
                              hipStream_t stream)
{
    const void* xyz1    = d_in[0];
    const void* xyz2    = d_in[1];
    const void* points1 = d_in[2];
    const void* points2 = d_in[3];
    const void* W0 = d_in[4];  const void* b0 = d_in[5];
    const void* g0 = d_in[6];  const void* bt0 = d_in[7];
    const void* W1 = d_in[8];  const void* b1 = d_in[9];
    const void* g1 = d_in[10]; const void* bt1 = d_in[11];

    // ws layout (total 112,541,696 B)
    char* ws = (char*)d_ws;
    float* stats = (float*)ws;                     //      4,096 B (1024 f)
    u32* flag    = (u32*)(ws + 4096);              //          4 B
    float* pf    = (float*)(ws + 8192);            //      6,144 B (b0,g0,bt0,b1,g1,bt1)
    u16* Wb0     = (u16*)(ws + 16384);             //    196,608 B
    u16* Wb1     = (u16*)(ws + 212992);            //    131,072 B
    u32* idxA    = (u32*)(ws + 344064);            //  1,572,864 B
    float* wA    = (float*)(ws + 1916928);         //  1,572,864 B
    u16* p2T     = (u16*)(ws + 3489792);           //  8,388,608 B
    u16* hT      = (u16*)(ws + 11878400);          // 100,663,296 B (131072 x 384)
    u16* h2      = hT;                             // alias: hT dead after gemm1
    float* sum0 = stats, *sq0 = stats + 256, *sum1 = stats + 512, *sq1 = stats + 768;

    // knn candidate table scratch lives inside d_out (dead until gemm0 writes it):
    // 8 batches x 2048 x float4 = 256 KiB at d_out+8MiB (out >= 64 MiB either dtype)
    float4* s2q = (float4*)((char*)d_out + (8u << 20));

    if (ws_size < (size_t)112541696) {
        sentinel_kernel<<<(out_size + 255) / 256, 256, 0, stream>>>((u16*)d_out, out_size);
        return;
    }

    // always-on mini sentinel: overwritten by gemm1/gemm2 if the pipeline runs
    sentinel_kernel<<<16, 256, 0, stream>>>((u16*)d_out, 4096);

    detect_kernel<<<1, 256, 0, stream>>>((const u32*)xyz1, flag, stats);
    param_kernel<<<384, 256, 0, stream>>>(W0, b0, g0, bt0, W1, b1, g1, bt1, flag, Wb0, Wb1, pf);
    pack2_kernel<<<64, 256, 0, stream>>>(xyz2, s2q, flag);
    transpose_kernel<<<dim3(32, 4, 8), 256, 0, stream>>>(points2, p2T, 256, 2048, 256, 0, flag);
    transpose_kernel<<<dim3(256, 2, 8), 256, 0, stream>>>(points1, hT, 128, 16384, 384, 256, flag);
    knn_kernel<<<2048, 256, 0, stream>>>(s2q, xyz1, idxA, wA, flag);
    interp_kernel<<<16384, 256, 0, stream>>>(p2T, idxA, wA, hT);
    gemm_kernel<<<dim3(1024, 2), 256, 0, stream>>>(Wb0, hT, pf + 0, d_out, 384, flag, sum0, sq0);
    bn_act_tr_kernel<<<dim3(2048, 4), 256, 0, stream>>>(d_out, sum0, sq0, pf + 256, pf + 512, h2, flag);
    gemm_kernel<<<dim3(1024, 2), 256, 0, stream>>>(Wb1, h2, pf + 768, d_out, 256, flag, sum1, sq1);
    final_kernel<<<32768, 256, 0, stream>>>(d_out, sum1, sq1, pf + 1024, pf + 1280, flag);
}

// Round 7
// 534.406 us; speedup vs baseline: 1.0292x; 1.0292x over previous
//
#include <hip/hip_runtime.h>
#include <hip/hip_bf16.h>

// ROUND 12: cut the y0 round-trip. r11 lesson: conflicts 3.1M->0 and 1-deep
// pipeline gave NO speedup (94->102; occupancy fell with 2x LDS) -> gemm is
// concurrency-bound moving compulsory bytes at ~2.3 TB/s. So shrink bytes:
//  - gemm0 (outmode=1): epilogue LDS-transposes the 128x128 tile and writes
//    h0 = bf16 n-major [n][256] (64 MiB) straight into d_out (dead until
//    gemm1 rewrites it; fits both output dtypes). Stats still fp32-exact.
//    Write 134->64 MiB and coalesced.
//  - bn_act_tr replaced by bn_elem: elementwise affine+relu on h0 -> h2 bf16
//    [n][256] into the ws hT region (hT dead after gemm0). 128 MiB total,
//    no LDS transpose.
//  - gemm1 (outmode=0): reads h2 from ws, writes fp32/u16 c-major d_out
//    (h0 dead after bn_elem). final unchanged.
// Numeric delta: y0 rounded to bf16 pre-BN (~2^-9 rel); h2 was already bf16.
// Epilogue tile ld=136 u16 (rows 16B-aligned, <=2-way banks).
// knn (82us) and all input-side kernels: round 11 verbatim.

typedef unsigned int u32;
typedef unsigned short u16;
typedef unsigned long long u64;
typedef __attribute__((ext_vector_type(8))) short short8;   // 8 x bf16 bits
typedef __attribute__((ext_vector_type(4))) float f32x4;

#define NT_TOTAL 131072   // B*N flattened columns
#define NN 16384
#define SS 2048

__device__ __forceinline__ float bf2f(u16 u) {
    union { u32 i; float f; } cv; cv.i = ((u32)u) << 16; return cv.f;
}
__device__ __forceinline__ u16 f2bf(float f) {
    union { float f; u32 i; } cv; cv.f = f;
    const u32 r = (cv.i + 0x7FFFu + ((cv.i >> 16) & 1u)) >> 16;   // RNE
    return (u16)r;
}
// dual-dtype scalar load (isbf wave-uniform)
__device__ __forceinline__ float ldf(const void* p, int i, int isbf) {
    return isbf ? bf2f(((const u16*)p)[i]) : ((const float*)p)[i];
}

// ---------------- detect dtype + zero stats (1 block, 256 thr) -----------------------
__global__ __launch_bounds__(256)
void detect_kernel(const u32* __restrict__ xyz1w, u32* __restrict__ flag,
                   float* __restrict__ stats)
{
    __shared__ int cnt;
    const int t = threadIdx.x;
    if (t == 0) cnt = 0;
    for (int i = t; i < 1024; i += 256) stats[i] = 0.f;
    __syncthreads();
    if (t < 64) {
        const u32 w = xyz1w[t];
        const int e = (int)((w >> 7) & 0xFF);   // bf16 exponent of LOW u16
        if (e >= 96 && e <= 144) atomicAdd(&cnt, 1);
    }
    __syncthreads();
    if (t == 0) flag[0] = (cnt >= 48) ? 1u : 0u;   // p~1 if packed bf16, p~0.19 if fp32
}

// ---------------- sentinel fill (u16 pattern 0x4496 ~ 1200) --------------------------
__global__ __launch_bounds__(256)
void sentinel_kernel(u16* __restrict__ out, int n)
{
    const int i = blockIdx.x * 256 + threadIdx.x;
    if (i < n) out[i] = 0x4496;
}

// ---------------- convert W -> bf16, params -> fp32 ----------------------------------
__global__ __launch_bounds__(256)
void param_kernel(const void* W0, const void* b0, const void* g0, const void* bt0,
                  const void* W1, const void* b1, const void* g1, const void* bt1,
                  const u32* __restrict__ flag,
                  u16* __restrict__ Wb0, u16* __restrict__ Wb1, float* __restrict__ pf)
{
    const int isbf = (int)flag[0];
    const int i = blockIdx.x * 256 + threadIdx.x;   // up to 98304
    if (i < 98304) Wb0[i] = f2bf(ldf(W0, i, isbf));
    if (i < 65536) Wb1[i] = f2bf(ldf(W1, i, isbf));
    if (i < 1536) {
        const void* srcs[6] = { b0, g0, bt0, b1, g1, bt1 };
        pf[i] = ldf(srcs[i >> 8], i & 255, isbf);
    }
}

// ---------------- pack xyz2 -> float4(x,y,z,|s|^2) -----------------------------------
__global__ __launch_bounds__(256)
void pack2_kernel(const void* __restrict__ xyz2, float4* __restrict__ s2q,
                  const u32* __restrict__ flag)
{
    const int isbf = (int)flag[0];
    const int i = blockIdx.x * 256 + threadIdx.x;   // 8*2048 points
    if (i < 8 * SS) {
        const float x = ldf(xyz2, i * 3 + 0, isbf);
        const float y = ldf(xyz2, i * 3 + 1, isbf);
        const float z = ldf(xyz2, i * 3 + 2, isbf);
        float4 v; v.x = x; v.y = y; v.z = z; v.w = x * x + y * y + z * z;
        s2q[i] = v;
    }
}

// ---------------- transpose (bz,Cc,Np) -> bf16 out[(bz*Np+n)*ldout+coff+c] -----------
__global__ __launch_bounds__(256)
void transpose_kernel(const void* __restrict__ in, u16* __restrict__ out,
                      int Cc, int Np, int ldout, int coff, const u32* __restrict__ flag)
{
    __shared__ u16 tile[64][72];
    const int isbf = (int)flag[0];
    const int t = threadIdx.x;
    const int n0 = blockIdx.x * 64, c0 = blockIdx.y * 64, bz = blockIdx.z;
    const int ch = t & 7, r = t >> 3;     // r: 0..31
#pragma unroll
    for (int p = 0; p < 2; ++p) {
        const int cl = r + p * 32;
        const size_t idx = ((size_t)(bz * Cc + c0 + cl)) * Np + n0 + ch * 8;
        union { uint4 v; u16 us[8]; } pk;
        if (isbf) {
            pk.v = *(const uint4*)((const u16*)in + idx);
        } else {
            const float4 va = *(const float4*)((const float*)in + idx);
            const float4 vb = *(const float4*)((const float*)in + idx + 4);
            pk.us[0] = f2bf(va.x); pk.us[1] = f2bf(va.y);
            pk.us[2] = f2bf(va.z); pk.us[3] = f2bf(va.w);
            pk.us[4] = f2bf(vb.x); pk.us[5] = f2bf(vb.y);
            pk.us[6] = f2bf(vb.z); pk.us[7] = f2bf(vb.w);
        }
        *(uint4*)&tile[cl][ch * 8] = pk.v;
    }
    __syncthreads();
#pragma unroll
    for (int p = 0; p < 2; ++p) {
        const int nl = r + p * 32;
        union { uint4 v; u16 us[8]; } pk;
#pragma unroll
        for (int i = 0; i < 8; ++i) pk.us[i] = tile[ch * 8 + i][nl];
        *(uint4*)&out[((size_t)(bz * Np + n0 + nl)) * ldout + coff + c0 + ch * 8] = pk.v;
    }
}

// ---------------- knn v5: 4-wave split + FORCED-uniform s_load + exact refine --------
__global__ __launch_bounds__(256)
void knn_kernel(const float4* __restrict__ s2q, const void* __restrict__ xyz1,
                u32* __restrict__ idxA, float* __restrict__ wA,
                const u32* __restrict__ flag)
{
    __shared__ float skeys[4][64][5];
    const int isbf = (int)flag[0];
    const int t = threadIdx.x;
    const int lane = t & 63;
    const int wid = __builtin_amdgcn_readfirstlane(t >> 6);   // provably uniform
    const int qg = blockIdx.x * 64 + lane;         // 64 queries per block
    const int b = blockIdx.x >> 8;                 // 256 blocks per batch
    const float qx = ldf(xyz1, qg * 3 + 0, isbf);
    const float qy = ldf(xyz1, qg * 3 + 1, isbf);
    const float qz = ldf(xyz1, qg * 3 + 2, isbf);
    const float qx2 = -2.f * qx, qy2 = -2.f * qy, qz2 = -2.f * qz;
    const float qc = qx * qx + qy * qy + qz * qz;   // |q|^2
    const float4* __restrict__ S = s2q + (size_t)b * SS;

    // sorted top-5 of packed keys: key = (d_bits & ~0x7FF) | s  (fp32 compare)
    float k0 = __builtin_inff(), k1 = k0, k2 = k0, k3 = k0, k4 = k0;
    const int sbase = wid * 512;                    // SGPR
#pragma unroll 8
    for (int it = 0; it < 512; ++it) {
        const int s = sbase + it;
        const float4 v = S[s];                      // uniform -> s_load_dwordx4
        float d = fmaf(v.x, qx2, qc);
        d = fmaf(v.y, qy2, d);
        d = fmaf(v.z, qz2, d);
        d += v.w;                                   // |q|^2 - 2 q.s + |s|^2
        const float k = __uint_as_float((__float_as_uint(d) & 0xFFFFF800u) | (u32)s);
        const float o0 = fminf(k, k0);
        const float o1 = __builtin_amdgcn_fmed3f(k, k0, k1);
        const float o2 = __builtin_amdgcn_fmed3f(k, k1, k2);
        const float o3 = __builtin_amdgcn_fmed3f(k, k2, k3);
        const float o4 = __builtin_amdgcn_fmed3f(k, k3, k4);
        k0 = o0; k1 = o1; k2 = o2; k3 = o3; k4 = o4;
    }
    skeys[wid][lane][0] = k0;
    skeys[wid][lane][1] = k1;
    skeys[wid][lane][2] = k2;
    skeys[wid][lane][3] = k3;
    skeys[wid][lane][4] = k4;
    __syncthreads();
    if (wid != 0) return;

    // exact refine: recompute subtract-form distances for the 20 survivors,
    // select top-3 on u64 key (d_bits<<11 | idx) -> exact values + tie->low idx
    u64 e0 = ~0ull, e1 = ~0ull, e2 = ~0ull;
#pragma unroll
    for (int w = 0; w < 4; ++w)
#pragma unroll
        for (int i = 0; i < 5; ++i) {
            const u32 idx = __float_as_uint(skeys[w][lane][i]) & 0x7FFu;
            const float4 c = S[idx];                 // per-lane gather (L1/L2 hit)
            const float dx = qx - c.x, dy = qy - c.y, dz = qz - c.z;
            const float d = fmaf(dz, dz, fmaf(dy, dy, dx * dx));   // exact, >= 0
            const u64 e = ((u64)__float_as_uint(d) << 11) | (u64)idx;
            const bool c0 = e < e0, c1 = e < e1, c2 = e < e2;
            e2 = c1 ? e1 : (c2 ? e : e2);
            e1 = c0 ? e0 : (c1 ? e : e1);
            e0 = c0 ? e : e0;
        }
    const u32 i0 = (u32)(e0 & 0x7FF), i1 = (u32)(e1 & 0x7FF), i2 = (u32)(e2 & 0x7FF);
    const float d0 = fmaxf(__uint_as_float((u32)(e0 >> 11)), 1e-10f);
    const float d1 = fmaxf(__uint_as_float((u32)(e1 >> 11)), 1e-10f);
    const float d2 = fmaxf(__uint_as_float((u32)(e2 >> 11)), 1e-10f);
    const float w0 = 1.f / d0, w1 = 1.f / d1, w2 = 1.f / d2;
    const float inv = 1.f / (w0 + w1 + w2);
    idxA[qg * 3 + 0] = i0; idxA[qg * 3 + 1] = i1; idxA[qg * 3 + 2] = i2;
    wA[qg * 3 + 0] = w0 * inv; wA[qg * 3 + 1] = w1 * inv; wA[qg * 3 + 2] = w2 * inv;
}

// ---------------- interp: hT[n][0..255] = sum_k w_k * p2T[b][idx_k][c] (bf16) --------
__global__ __launch_bounds__(256)
void interp_kernel(const u16* __restrict__ p2T, const u32* __restrict__ idxA,
                   const float* __restrict__ wA, u16* __restrict__ hT)
{
    const int t = threadIdx.x;
    const int pl = t >> 5, g = t & 31;           // 8 points/block, 32 lanes/point
    const int qg = blockIdx.x * 8 + pl;
    const int b = qg >> 14;
    float acc[8] = {0.f, 0.f, 0.f, 0.f, 0.f, 0.f, 0.f, 0.f};
#pragma unroll
    for (int k = 0; k < 3; ++k) {
        const u32 idx = idxA[qg * 3 + k];
        const float w = wA[qg * 3 + k];
        union { uint4 v; u16 us[8]; } pk;
        pk.v = *(const uint4*)(p2T + ((size_t)(b * SS + idx)) * 256 + g * 8);
#pragma unroll
        for (int e = 0; e < 8; ++e) acc[e] = fmaf(w, bf2f(pk.us[e]), acc[e]);
    }
    union { uint4 v; u16 us[8]; } ov;
#pragma unroll
    for (int e = 0; e < 8; ++e) ov.us[e] = f2bf(acc[e]);
    *(uint4*)&hT[(size_t)qg * 384 + g * 8] = ov.v;
}

// ---------------- GEMM (pipelined, swizzled) + fused BN-stats ------------------------
// outmode 0: write fp32/u16 c-major to yout (layer 1).
// outmode 1: write bf16 n-major [n][256] to yout via LDS transpose (layer 0).
// Stats (fp32, pre-rounding) accumulated into sums/sumsq in both modes.
#define GEMM_BODY(BUF, OTH, KCUR)                                                        \
    {                                                                                    \
        short8 a[4], b[4];                                                               \
        _Pragma("unroll")                                                                \
        for (int i = 0; i < 4; ++i) a[i] = *(const short8*)&aT[BUF][aoff[i]];            \
        _Pragma("unroll")                                                                \
        for (int j = 0; j < 4; ++j) b[j] = *(const short8*)&bT[BUF][boff[j]];            \
        _Pragma("unroll")                                                                \
        for (int i = 0; i < 4; ++i)                                                      \
            _Pragma("unroll")                                                            \
            for (int j = 0; j < 4; ++j)                                                  \
                acc[i][j] = __builtin_amdgcn_mfma_f32_16x16x32_bf16(a[i], b[j], acc[i][j], 0, 0, 0); \
        if ((KCUR) + 32 < K) {                                                           \
            *(uint4*)&aT[OTH][o0] = ra0; *(uint4*)&aT[OTH][o1] = ra1;                    \
            *(uint4*)&bT[OTH][o0] = rb0; *(uint4*)&bT[OTH][o1] = rb1;                    \
            if ((KCUR) + 64 < K) {                                                       \
                ra0 = *(const uint4*)(gA0 + (KCUR) + 64);                                \
                ra1 = *(const uint4*)(gA1 + (KCUR) + 64);                                \
                rb0 = *(const uint4*)(gB0 + (KCUR) + 64);                                \
                rb1 = *(const uint4*)(gB1 + (KCUR) + 64);                                \
            }                                                                            \
        }                                                                                \
        __syncthreads();                                                                 \
    }

__global__ __launch_bounds__(256)
void gemm_kernel(const u16* __restrict__ A, const u16* __restrict__ Bm,
                 const float* __restrict__ bias, void* __restrict__ yout, int K,
                 const u32* __restrict__ flag,
                 float* __restrict__ sums, float* __restrict__ sumsq, int outmode)
{
    // unioned LDS: K-loop staging uses [0,16384) u16; epilogue tile 128x136
    // uses [0,17408); stats floats live at [17408,18432) u16 (disjoint).
    __shared__ __align__(16) u16 lds[18432];
    u16* const aT[2] = { lds, lds + 4096 };
    u16* const bT[2] = { lds + 8192, lds + 12288 };
    float* const sds = (float*)(lds + 17408);

    const int isbf = (int)flag[0];
    const int t = threadIdx.x;
    const int lane = t & 63;
    const int l15 = lane & 15;
    const int q = lane >> 4;
    const int wid = t >> 6;
    const int n0 = blockIdx.x * 128;
    const int m0 = blockIdx.y * 128;
    const int wm = (wid & 1) * 64;
    const int wn = (wid >> 1) * 64;
    const int wp = wid >> 1;

    f32x4 acc[4][4] = {};

    // staging chunks: ca0=t (rows 0..63), ca1=t+256 (rows 64..127); granule swizzle
    const int ca0 = t, ca1 = t + 256;
    const u16* gA0 = A + (size_t)(m0 + (ca0 >> 2)) * K + (ca0 & 3) * 8;
    const u16* gA1 = A + (size_t)(m0 + (ca1 >> 2)) * K + (ca1 & 3) * 8;
    const u16* gB0 = Bm + (size_t)(n0 + (ca0 >> 2)) * K + (ca0 & 3) * 8;
    const u16* gB1 = Bm + (size_t)(n0 + (ca1 >> 2)) * K + (ca1 & 3) * 8;
    const int o0 = (ca0 >> 2) * 32 + (((ca0 & 3) ^ ((ca0 >> 3) & 3)) * 8);
    const int o1 = (ca1 >> 2) * 32 + (((ca1 & 3) ^ ((ca1 >> 3) & 3)) * 8);

    // fragment read offsets (logical granule q lives at physical q^gsw)
    const int gsw = (l15 >> 1) & 3;
    int aoff[4], boff[4];
#pragma unroll
    for (int i = 0; i < 4; ++i) {
        aoff[i] = (wm + i * 16 + l15) * 32 + ((q ^ gsw) * 8);
        boff[i] = (wn + i * 16 + l15) * 32 + ((q ^ gsw) * 8);
    }

    // prologue: tile 0 -> buf0; prefetch tile 1 into regs
    uint4 ra0 = *(const uint4*)(gA0);
    uint4 ra1 = *(const uint4*)(gA1);
    uint4 rb0 = *(const uint4*)(gB0);
    uint4 rb1 = *(const uint4*)(gB1);
    *(uint4*)&aT[0][o0] = ra0; *(uint4*)&aT[0][o1] = ra1;
    *(uint4*)&bT[0][o0] = rb0; *(uint4*)&bT[0][o1] = rb1;
    ra0 = *(const uint4*)(gA0 + 32);
    ra1 = *(const uint4*)(gA1 + 32);
    rb0 = *(const uint4*)(gB0 + 32);
    rb1 = *(const uint4*)(gB1 + 32);
    __syncthreads();

    for (int kk = 0; kk < K; kk += 64) {
        GEMM_BODY(0, 1, kk)
        GEMM_BODY(1, 0, kk + 32)
    }

    if (outmode) {
        // ---- layer-0 epilogue: stats + bf16 n-major via LDS transpose ----
#pragma unroll
        for (int i = 0; i < 4; ++i) {
            const int mloc = wm + i * 16 + q * 4;     // channel - m0
            float bi[4];
#pragma unroll
            for (int r = 0; r < 4; ++r) bi[r] = bias[m0 + mloc + r];
#pragma unroll
            for (int r = 0; r < 4; ++r) {
                float s = 0.f, sq = 0.f;
#pragma unroll
                for (int j = 0; j < 4; ++j) {
                    const float v = acc[i][j][r] + bi[r];
                    s += v; sq += v * v;
                }
#pragma unroll
                for (int off = 1; off < 16; off <<= 1) {
                    s += __shfl_xor(s, off);
                    sq += __shfl_xor(sq, off);
                }
                if (l15 == 0) {
                    sds[wp * 128 + mloc + r] = s;
                    sds[256 + wp * 128 + mloc + r] = sq;
                }
            }
#pragma unroll
            for (int j = 0; j < 4; ++j) {
                const int nl = wn + j * 16 + l15;
                union { u64 w; u16 us[4]; } pk;
#pragma unroll
                for (int r = 0; r < 4; ++r) pk.us[r] = f2bf(acc[i][j][r] + bi[r]);
                *(u64*)&lds[nl * 136 + mloc] = pk.w;      // 8B-aligned
            }
        }
        __syncthreads();
        // read out n-major rows, coalesced global bf16 store
        u16* outp = (u16*)yout;
#pragma unroll
        for (int it = 0; it < 8; ++it) {
            const int row = (t >> 4) + it * 16;
            const int cc = (t & 15) * 8;
            const uint4 v = *(const uint4*)&lds[row * 136 + cc];   // 16B-aligned (136*2=272=16*17)
            *(uint4*)&outp[((size_t)(n0 + row)) * 256 + m0 + cc] = v;
        }
        if (t < 128) {
            atomicAdd(&sums[m0 + t], sds[t] + sds[128 + t]);
        } else if (t < 256) {
            const int c = t - 128;
            atomicAdd(&sumsq[m0 + c], sds[256 + c] + sds[384 + c]);
        }
        return;
    }

    // ---- layer-1 epilogue: fp32/u16 c-major store + stats (round 11 path) ----
#pragma unroll
    for (int i = 0; i < 4; ++i) {
        const int mBase = m0 + wm + i * 16 + q * 4;   // D row = q*4+reg
        float bi[4];
#pragma unroll
        for (int r = 0; r < 4; ++r) bi[r] = bias[mBase + r];
#pragma unroll
        for (int j = 0; j < 4; ++j) {
            const int col = n0 + wn + j * 16 + l15;    // D col = lane&15
            const size_t obase = ((size_t)(col >> 14) * 256) * NN + (col & 16383);
#pragma unroll
            for (int r = 0; r < 4; ++r) {
                const float v = acc[i][j][r] + bi[r];
                const size_t oi = obase + (size_t)(mBase + r) * NN;
                if (isbf) ((u16*)yout)[oi] = f2bf(v);
                else      ((float*)yout)[oi] = v;
            }
        }
    }
#pragma unroll
    for (int i = 0; i < 4; ++i) {
        const int mloc = wm + i * 16 + q * 4;
#pragma unroll
        for (int r = 0; r < 4; ++r) {
            const float bi = bias[m0 + mloc + r];
            float s = 0.f, sq = 0.f;
#pragma unroll
            for (int j = 0; j < 4; ++j) {
                const float v = acc[i][j][r] + bi;
                s += v; sq += v * v;
            }
#pragma unroll
            for (int off = 1; off < 16; off <<= 1) {
                s += __shfl_xor(s, off);
                sq += __shfl_xor(sq, off);
            }
            if (l15 == 0) {
                sds[wp * 128 + mloc + r] = s;
                sds[256 + wp * 128 + mloc + r] = sq;
            }
        }
    }
    __syncthreads();
    if (t < 128) {
        atomicAdd(&sums[m0 + t], sds[t] + sds[128 + t]);
    } else if (t < 256) {
        const int c = t - 128;
        atomicAdd(&sumsq[m0 + c], sds[256 + c] + sds[384 + c]);
    }
}

// ---------------- BN + ReLU elementwise: h0 bf16 [n][256] -> h2 bf16 [n][256] --------
__global__ __launch_bounds__(256)
void bn_elem_kernel(const u16* __restrict__ h0, const float* __restrict__ sums,
                    const float* __restrict__ sumsq, const float* __restrict__ gam,
                    const float* __restrict__ beta, u16* __restrict__ h2)
{
    __shared__ float ssc[256], ssh[256];
    const int t = threadIdx.x;
    {
        const float invNT = 1.0f / (float)NT_TOTAL;
        const float mean = sums[t] * invNT;
        const float var = sumsq[t] * invNT - mean * mean;
        const float rstd = rsqrtf(var + 1e-5f);
        const float sc = gam[t] * rstd;
        ssc[t] = sc;
        ssh[t] = beta[t] - mean * sc;
    }
    __syncthreads();
    // 131072*256 elems = 4,194,304 uint4 chunks; 4096 blocks x 256 thr x 4 iters
    for (u32 g = blockIdx.x * 256 + t; g < 4194304u; g += 4096u * 256u) {
        const int cb = (g & 31) * 8;
        union { uint4 v; u16 us[8]; } iv, ov;
        iv.v = *(const uint4*)(h0 + (size_t)g * 8);
#pragma unroll
        for (int e = 0; e < 8; ++e) {
            float v = bf2f(iv.us[e]) * ssc[cb + e] + ssh[cb + e];
            v = (v != v) ? 777.0f : fmaxf(v, 0.f);   // NaN canary
            ov.us[e] = f2bf(v);
        }
        *(uint4*)(h2 + (size_t)g * 8) = ov.v;
    }
}

// ---------------- final BN + ReLU, IN-PLACE on d_out ---------------------------------
__global__ __launch_bounds__(256)
void final_kernel(void* __restrict__ y, const float* __restrict__ sums,
                  const float* __restrict__ sumsq, const float* __restrict__ gam,
                  const float* __restrict__ beta, const u32* __restrict__ flag)
{
    const int isbf = (int)flag[0];
    const int gid = blockIdx.x * 256 + threadIdx.x;   // x4 elements
    const int c = (gid >> 12) & 255;
    const float invNT = 1.0f / (float)NT_TOTAL;
    const float mean = sums[c] * invNT;
    const float var = sumsq[c] * invNT - mean * mean;
    const float rstd = rsqrtf(var + 1e-5f);
    const float sc = gam[c] * rstd;
    const float sh = beta[c] - mean * sc;
    const size_t idx4 = (size_t)gid * 4;
    float in4[4];
    if (isbf) {
        union { uint2 v2; u16 us[4]; } iv;
        iv.v2 = *(const uint2*)((const u16*)y + idx4);
#pragma unroll
        for (int e = 0; e < 4; ++e) in4[e] = bf2f(iv.us[e]);
    } else {
        const float4 v = *(const float4*)((const float*)y + idx4);
        in4[0] = v.x; in4[1] = v.y; in4[2] = v.z; in4[3] = v.w;
    }
    float o4[4];
#pragma unroll
    for (int e = 0; e < 4; ++e) {
        float v = in4[e] * sc + sh;
        o4[e] = (v != v) ? 777.0f : fmaxf(v, 0.f);    // NaN canary
    }
    if (isbf) {
        union { uint2 v2; u16 us[4]; } o;
#pragma unroll
        for (int e = 0; e < 4; ++e) o.us[e] = f2bf(o4[e]);
        *(uint2*)((u16*)y + idx4) = o.v2;
    } else {
        float4 o; o.x = o4[0]; o.y = o4[1]; o.z = o4[2]; o.w = o4[3];
        *(float4*)((float*)y + idx4) = o;
    }
}

// kept in case the harness expects this symbol to exist (never launched)
__global__ void pointnet_fp_module_24532853195517_kernel() {}

extern "C" void kernel_launch(void* const* d_in, const int* in_sizes, int n_in,
                              void* d_out, int out_size, void* d_ws, size_t ws_size,
                              hipStream_t stream)
{
    const void* xyz1    = d_in[0];
    const void* xyz2    = d_in[1];
    const void* points1 = d_in[2];
    const void* points2 = d_in[3];
    const void* W0 = d_in[4];  const void* b0 = d_in[5];
    const void* g0 = d_in[6];  const void* bt0 = d_in[7];
    const void* W1 = d_in[8];  const void* b1 = d_in[9];
    const void* g1 = d_in[10]; const void* bt1 = d_in[11];

    // ws layout (total 112,541,696 B)
    char* ws = (char*)d_ws;
    float* stats = (float*)ws;                     //      4,096 B (1024 f)
    u32* flag    = (u32*)(ws + 4096);              //          4 B
    float* pf    = (float*)(ws + 8192);            //      6,144 B (b0,g0,bt0,b1,g1,bt1)
    u16* Wb0     = (u16*)(ws + 16384);             //    196,608 B
    u16* Wb1     = (u16*)(ws + 212992);            //    131,072 B
    u32* idxA    = (u32*)(ws + 344064);            //  1,572,864 B
    float* wA    = (float*)(ws + 1916928);         //  1,572,864 B
    u16* p2T     = (u16*)(ws + 3489792);           //  8,388,608 B
    u16* hT      = (u16*)(ws + 11878400);          // 100,663,296 B (131072 x 384)
    u16* h2      = hT;                             // reuse: hT dead after gemm0
    float* sum0 = stats, *sq0 = stats + 256, *sum1 = stats + 512, *sq1 = stats + 768;

    // h0 (layer-0 bf16 n-major output, 64 MiB) lives in d_out (dead until gemm1);
    // knn s2q scratch at d_out+8MiB (dead after knn, before gemm0 writes h0)
    u16* h0 = (u16*)d_out;
    float4* s2q = (float4*)((char*)d_out + (8u << 20));

    if (ws_size < (size_t)112541696) {
        sentinel_kernel<<<(out_size + 255) / 256, 256, 0, stream>>>((u16*)d_out, out_size);
        return;
    }

    // always-on mini sentinel: overwritten by the pipeline if it runs
    sentinel_kernel<<<16, 256, 0, stream>>>((u16*)d_out, 4096);

    detect_kernel<<<1, 256, 0, stream>>>((const u32*)xyz1, flag, stats);
    param_kernel<<<384, 256, 0, stream>>>(W0, b0, g0, bt0, W1, b1, g1, bt1, flag, Wb0, Wb1, pf);
    pack2_kernel<<<64, 256, 0, stream>>>(xyz2, s2q, flag);
    transpose_kernel<<<dim3(32, 4, 8), 256, 0, stream>>>(points2, p2T, 256, 2048, 256, 0, flag);
    transpose_kernel<<<dim3(256, 2, 8), 256, 0, stream>>>(points1, hT, 128, 16384, 384, 256, flag);
    knn_kernel<<<2048, 256, 0, stream>>>(s2q, xyz1, idxA, wA, flag);
    interp_kernel<<<16384, 256, 0, stream>>>(p2T, idxA, wA, hT);
    gemm_kernel<<<dim3(1024, 2), 256, 0, stream>>>(Wb0, hT, pf + 0, h0, 384, flag, sum0, sq0, 1);
    bn_elem_kernel<<<4096, 256, 0, stream>>>(h0, sum0, sq0, pf + 256, pf + 512, h2);
    gemm_kernel<<<dim3(1024, 2), 256, 0, stream>>>(Wb1, h2, pf + 768, d_out, 256, flag, sum1, sq1, 0);
    final_kernel<<<32768, 256, 0, stream>>>(d_out, sum1, sq1, pf + 1024, pf + 1280, flag);
}

// Round 8
// 523.507 us; speedup vs baseline: 1.0507x; 1.0208x over previous
//
#include <hip/hip_runtime.h>
#include <hip/hip_bf16.h>

// ROUND 13: kill bn_elem by relocating h0 into hT (in-place) + fusing BN into
// gemm1's staging. r12 lesson: byte cuts inside the gemm loop don't shrink it
// (latency-bound, 92us at 23-27% HBM both before and after) -> only removing
// whole passes pays. bn_elem existed because h0 sat in d_out (gemm1 writes
// d_out). Now:
//  - gemm0: grid 2048, one block per 64-col slice, ALL 256 channels (4 waves x
//    64ch). B-rows are block-exclusive -> epilogue writes h0=f2bf(y0) IN-PLACE
//    into the first 256 u16 of the same hT rows (stride 384). Reads drain at
//    the last K-step barrier before any store. A (Wb0, L2-resident) direct to
//    regs (16rows x 64B coalesced, 1-ahead prefetch); B via LDS dbuf +
//    verified granule swizzle + 2-deep reg prefetch.
//  - gemm1: stages B from h0-in-hT applying f2bf(relu(bf2f(h0)*sc+sh)) -- the
//    bit-identical bn_elem transform -- with ssc/ssh computed in the prologue
//    from sum0/sq0. A direct-from-L2. Epilogue (c-major store + stats) as r12.
//  - bn_elem deleted. h0 bits, h2 values, MFMA order identical -> absmax
//    expected unchanged at 0.03125.
// knn (82us) and all input-side kernels: round 12 verbatim.

typedef unsigned int u32;
typedef unsigned short u16;
typedef unsigned long long u64;
typedef __attribute__((ext_vector_type(8))) short short8;   // 8 x bf16 bits
typedef __attribute__((ext_vector_type(4))) float f32x4;

#define NT_TOTAL 131072   // B*N flattened columns
#define NN 16384
#define SS 2048

__device__ __forceinline__ float bf2f(u16 u) {
    union { u32 i; float f; } cv; cv.i = ((u32)u) << 16; return cv.f;
}
__device__ __forceinline__ u16 f2bf(float f) {
    union { float f; u32 i; } cv; cv.f = f;
    const u32 r = (cv.i + 0x7FFFu + ((cv.i >> 16) & 1u)) >> 16;   // RNE
    return (u16)r;
}
// dual-dtype scalar load (isbf wave-uniform)
__device__ __forceinline__ float ldf(const void* p, int i, int isbf) {
    return isbf ? bf2f(((const u16*)p)[i]) : ((const float*)p)[i];
}

// ---------------- detect dtype + zero stats (1 block, 256 thr) -----------------------
__global__ __launch_bounds__(256)
void detect_kernel(const u32* __restrict__ xyz1w, u32* __restrict__ flag,
                   float* __restrict__ stats)
{
    __shared__ int cnt;
    const int t = threadIdx.x;
    if (t == 0) cnt = 0;
    for (int i = t; i < 1024; i += 256) stats[i] = 0.f;
    __syncthreads();
    if (t < 64) {
        const u32 w = xyz1w[t];
        const int e = (int)((w >> 7) & 0xFF);   // bf16 exponent of LOW u16
        if (e >= 96 && e <= 144) atomicAdd(&cnt, 1);
    }
    __syncthreads();
    if (t == 0) flag[0] = (cnt >= 48) ? 1u : 0u;   // p~1 if packed bf16, p~0.19 if fp32
}

// ---------------- sentinel fill (u16 pattern 0x4496 ~ 1200) --------------------------
__global__ __launch_bounds__(256)
void sentinel_kernel(u16* __restrict__ out, int n)
{
    const int i = blockIdx.x * 256 + threadIdx.x;
    if (i < n) out[i] = 0x4496;
}

// ---------------- convert W -> bf16, params -> fp32 ----------------------------------
__global__ __launch_bounds__(256)
void param_kernel(const void* W0, const void* b0, const void* g0, const void* bt0,
                  const void* W1, const void* b1, const void* g1, const void* bt1,
                  const u32* __restrict__ flag,
                  u16* __restrict__ Wb0, u16* __restrict__ Wb1, float* __restrict__ pf)
{
    const int isbf = (int)flag[0];
    const int i = blockIdx.x * 256 + threadIdx.x;   // up to 98304
    if (i < 98304) Wb0[i] = f2bf(ldf(W0, i, isbf));
    if (i < 65536) Wb1[i] = f2bf(ldf(W1, i, isbf));
    if (i < 1536) {
        const void* srcs[6] = { b0, g0, bt0, b1, g1, bt1 };
        pf[i] = ldf(srcs[i >> 8], i & 255, isbf);
    }
}

// ---------------- pack xyz2 -> float4(x,y,z,|s|^2) -----------------------------------
__global__ __launch_bounds__(256)
void pack2_kernel(const void* __restrict__ xyz2, float4* __restrict__ s2q,
                  const u32* __restrict__ flag)
{
    const int isbf = (int)flag[0];
    const int i = blockIdx.x * 256 + threadIdx.x;   // 8*2048 points
    if (i < 8 * SS) {
        const float x = ldf(xyz2, i * 3 + 0, isbf);
        const float y = ldf(xyz2, i * 3 + 1, isbf);
        const float z = ldf(xyz2, i * 3 + 2, isbf);
        float4 v; v.x = x; v.y = y; v.z = z; v.w = x * x + y * y + z * z;
        s2q[i] = v;
    }
}

// ---------------- transpose (bz,Cc,Np) -> bf16 out[(bz*Np+n)*ldout+coff+c] -----------
__global__ __launch_bounds__(256)
void transpose_kernel(const void* __restrict__ in, u16* __restrict__ out,
                      int Cc, int Np, int ldout, int coff, const u32* __restrict__ flag)
{
    __shared__ u16 tile[64][72];
    const int isbf = (int)flag[0];
    const int t = threadIdx.x;
    const int n0 = blockIdx.x * 64, c0 = blockIdx.y * 64, bz = blockIdx.z;
    const int ch = t & 7, r = t >> 3;     // r: 0..31
#pragma unroll
    for (int p = 0; p < 2; ++p) {
        const int cl = r + p * 32;
        const size_t idx = ((size_t)(bz * Cc + c0 + cl)) * Np + n0 + ch * 8;
        union { uint4 v; u16 us[8]; } pk;
        if (isbf) {
            pk.v = *(const uint4*)((const u16*)in + idx);
        } else {
            const float4 va = *(const float4*)((const float*)in + idx);
            const float4 vb = *(const float4*)((const float*)in + idx + 4);
            pk.us[0] = f2bf(va.x); pk.us[1] = f2bf(va.y);
            pk.us[2] = f2bf(va.z); pk.us[3] = f2bf(va.w);
            pk.us[4] = f2bf(vb.x); pk.us[5] = f2bf(vb.y);
            pk.us[6] = f2bf(vb.z); pk.us[7] = f2bf(vb.w);
        }
        *(uint4*)&tile[cl][ch * 8] = pk.v;
    }
    __syncthreads();
#pragma unroll
    for (int p = 0; p < 2; ++p) {
        const int nl = r + p * 32;
        union { uint4 v; u16 us[8]; } pk;
#pragma unroll
        for (int i = 0; i < 8; ++i) pk.us[i] = tile[ch * 8 + i][nl];
        *(uint4*)&out[((size_t)(bz * Np + n0 + nl)) * ldout + coff + c0 + ch * 8] = pk.v;
    }
}

// ---------------- knn v5: 4-wave split + FORCED-uniform s_load + exact refine --------
__global__ __launch_bounds__(256)
void knn_kernel(const float4* __restrict__ s2q, const void* __restrict__ xyz1,
                u32* __restrict__ idxA, float* __restrict__ wA,
                const u32* __restrict__ flag)
{
    __shared__ float skeys[4][64][5];
    const int isbf = (int)flag[0];
    const int t = threadIdx.x;
    const int lane = t & 63;
    const int wid = __builtin_amdgcn_readfirstlane(t >> 6);   // provably uniform
    const int qg = blockIdx.x * 64 + lane;         // 64 queries per block
    const int b = blockIdx.x >> 8;                 // 256 blocks per batch
    const float qx = ldf(xyz1, qg * 3 + 0, isbf);
    const float qy = ldf(xyz1, qg * 3 + 1, isbf);
    const float qz = ldf(xyz1, qg * 3 + 2, isbf);
    const float qx2 = -2.f * qx, qy2 = -2.f * qy, qz2 = -2.f * qz;
    const float qc = qx * qx + qy * qy + qz * qz;   // |q|^2
    const float4* __restrict__ S = s2q + (size_t)b * SS;

    // sorted top-5 of packed keys: key = (d_bits & ~0x7FF) | s  (fp32 compare)
    float k0 = __builtin_inff(), k1 = k0, k2 = k0, k3 = k0, k4 = k0;
    const int sbase = wid * 512;                    // SGPR
#pragma unroll 8
    for (int it = 0; it < 512; ++it) {
        const int s = sbase + it;
        const float4 v = S[s];                      // uniform -> s_load_dwordx4
        float d = fmaf(v.x, qx2, qc);
        d = fmaf(v.y, qy2, d);
        d = fmaf(v.z, qz2, d);
        d += v.w;                                   // |q|^2 - 2 q.s + |s|^2
        const float k = __uint_as_float((__float_as_uint(d) & 0xFFFFF800u) | (u32)s);
        const float o0 = fminf(k, k0);
        const float o1 = __builtin_amdgcn_fmed3f(k, k0, k1);
        const float o2 = __builtin_amdgcn_fmed3f(k, k1, k2);
        const float o3 = __builtin_amdgcn_fmed3f(k, k2, k3);
        const float o4 = __builtin_amdgcn_fmed3f(k, k3, k4);
        k0 = o0; k1 = o1; k2 = o2; k3 = o3; k4 = o4;
    }
    skeys[wid][lane][0] = k0;
    skeys[wid][lane][1] = k1;
    skeys[wid][lane][2] = k2;
    skeys[wid][lane][3] = k3;
    skeys[wid][lane][4] = k4;
    __syncthreads();
    if (wid != 0) return;

    // exact refine: recompute subtract-form distances for the 20 survivors,
    // select top-3 on u64 key (d_bits<<11 | idx) -> exact values + tie->low idx
    u64 e0 = ~0ull, e1 = ~0ull, e2 = ~0ull;
#pragma unroll
    for (int w = 0; w < 4; ++w)
#pragma unroll
        for (int i = 0; i < 5; ++i) {
            const u32 idx = __float_as_uint(skeys[w][lane][i]) & 0x7FFu;
            const float4 c = S[idx];                 // per-lane gather (L1/L2 hit)
            const float dx = qx - c.x, dy = qy - c.y, dz = qz - c.z;
            const float d = fmaf(dz, dz, fmaf(dy, dy, dx * dx));   // exact, >= 0
            const u64 e = ((u64)__float_as_uint(d) << 11) | (u64)idx;
            const bool c0 = e < e0, c1 = e < e1, c2 = e < e2;
            e2 = c1 ? e1 : (c2 ? e : e2);
            e1 = c0 ? e0 : (c1 ? e : e1);
            e0 = c0 ? e : e0;
        }
    const u32 i0 = (u32)(e0 & 0x7FF), i1 = (u32)(e1 & 0x7FF), i2 = (u32)(e2 & 0x7FF);
    const float d0 = fmaxf(__uint_as_float((u32)(e0 >> 11)), 1e-10f);
    const float d1 = fmaxf(__uint_as_float((u32)(e1 >> 11)), 1e-10f);
    const float d2 = fmaxf(__uint_as_float((u32)(e2 >> 11)), 1e-10f);
    const float w0 = 1.f / d0, w1 = 1.f / d1, w2 = 1.f / d2;
    const float inv = 1.f / (w0 + w1 + w2);
    idxA[qg * 3 + 0] = i0; idxA[qg * 3 + 1] = i1; idxA[qg * 3 + 2] = i2;
    wA[qg * 3 + 0] = w0 * inv; wA[qg * 3 + 1] = w1 * inv; wA[qg * 3 + 2] = w2 * inv;
}

// ---------------- interp: hT[n][0..255] = sum_k w_k * p2T[b][idx_k][c] (bf16) --------
__global__ __launch_bounds__(256)
void interp_kernel(const u16* __restrict__ p2T, const u32* __restrict__ idxA,
                   const float* __restrict__ wA, u16* __restrict__ hT)
{
    const int t = threadIdx.x;
    const int pl = t >> 5, g = t & 31;           // 8 points/block, 32 lanes/point
    const int qg = blockIdx.x * 8 + pl;
    const int b = qg >> 14;
    float acc[8] = {0.f, 0.f, 0.f, 0.f, 0.f, 0.f, 0.f, 0.f};
#pragma unroll
    for (int k = 0; k < 3; ++k) {
        const u32 idx = idxA[qg * 3 + k];
        const float w = wA[qg * 3 + k];
        union { uint4 v; u16 us[8]; } pk;
        pk.v = *(const uint4*)(p2T + ((size_t)(b * SS + idx)) * 256 + g * 8);
#pragma unroll
        for (int e = 0; e < 8; ++e) acc[e] = fmaf(w, bf2f(pk.us[e]), acc[e]);
    }
    union { uint4 v; u16 us[8]; } ov;
#pragma unroll
    for (int e = 0; e < 8; ++e) ov.us[e] = f2bf(acc[e]);
    *(uint4*)&hT[(size_t)qg * 384 + g * 8] = ov.v;
}

// ---------------- GEMM0: 64 cols x 256 ch per block, h0 in-place into hT -------------
// B-rows (hT rows n0..n0+64) are block-exclusive; epilogue overwrites their
// first 256 u16 with h0 = f2bf(y0). A = Wb0 (L2-resident) direct to regs.
#define K0 384
#define G0_STEP(BUF, OTH, KCUR, RAC, RAN, RBW)                                           \
    {                                                                                    \
        short8 a4[4], b4[4];                                                             \
        _Pragma("unroll")                                                                \
        for (int i = 0; i < 4; ++i) a4[i] = *(short8*)&RAC[i];                           \
        _Pragma("unroll")                                                                \
        for (int j = 0; j < 4; ++j)                                                      \
            b4[j] = *(const short8*)&bT[BUF][(j * 16 + l15) * 32 + (q ^ gsw) * 8];       \
        if ((KCUR) + 32 < K0) {                                                          \
            _Pragma("unroll")                                                            \
            for (int i = 0; i < 4; ++i)                                                  \
                RAN[i] = *(const uint4*)(gA + i * 16 * K0 + (KCUR) + 32);                \
        }                                                                                \
        _Pragma("unroll")                                                                \
        for (int i = 0; i < 4; ++i)                                                      \
            _Pragma("unroll")                                                            \
            for (int j = 0; j < 4; ++j)                                                  \
                acc[i][j] = __builtin_amdgcn_mfma_f32_16x16x32_bf16(a4[i], b4[j], acc[i][j], 0, 0, 0); \
        if ((KCUR) + 32 < K0) {                                                          \
            *(uint4*)&bT[OTH][ob] = RBW;                                                 \
            if ((KCUR) + 96 < K0) RBW = *(const uint4*)(gB + (KCUR) + 96);               \
        }                                                                                \
        __syncthreads();                                                                 \
    }

__global__ __launch_bounds__(256)
void gemm0_kernel(const u16* __restrict__ A, u16* __restrict__ hTio,
                  const float* __restrict__ bias,
                  float* __restrict__ sums, float* __restrict__ sumsq)
{
    __shared__ __align__(16) u16 bT[2][64 * 32];   // 2 x 4 KB
    __shared__ float sds[512];
    const int t = threadIdx.x;
    const int lane = t & 63;
    const int l15 = lane & 15;
    const int q = lane >> 4;
    const int wid = t >> 6;
    const int n0 = blockIdx.x * 64;
    const int wm = wid * 64;                       // wave-exclusive channel slice

    f32x4 acc[4][4] = {};

    // B staging: 1 chunk/thread/step; row = t>>2 (0..63), kc = (t&3)*8
    const u16* gB = hTio + (size_t)(n0 + (t >> 2)) * 384 + (t & 3) * 8;
    const int ob = (t >> 2) * 32 + (((t & 3) ^ ((t >> 3) & 3)) * 8);
    // A direct (L2): row wm+i*16+l15, k = kk + q*8
    const u16* gA = A + (size_t)(wm + l15) * K0 + q * 8;
    const int gsw = (l15 >> 1) & 3;

    uint4 raA[4], raB[4], rbA, rbB;
    {
        const uint4 r0 = *(const uint4*)gB;
#pragma unroll
        for (int i = 0; i < 4; ++i) raA[i] = *(const uint4*)(gA + i * 16 * K0);
        *(uint4*)&bT[0][ob] = r0;
        rbA = *(const uint4*)(gB + 32);
        rbB = *(const uint4*)(gB + 64);
        __syncthreads();
    }

#pragma unroll
    for (int kk = 0; kk < K0; kk += 64) {
        G0_STEP(0, 1, kk, raA, raB, rbA)
        G0_STEP(1, 0, kk + 32, raB, raA, rbB)
    }

    // epilogue: h0 in-place stores (all reads drained at last barrier) + stats
#pragma unroll
    for (int i = 0; i < 4; ++i) {
        const int mcb = wm + i * 16 + q * 4;
        float bi4[4];
#pragma unroll
        for (int r = 0; r < 4; ++r) bi4[r] = bias[mcb + r];
#pragma unroll
        for (int j = 0; j < 4; ++j) {
            const int nl = j * 16 + l15;
            union { u64 w; u16 us[4]; } pk;
#pragma unroll
            for (int r = 0; r < 4; ++r) pk.us[r] = f2bf(acc[i][j][r] + bi4[r]);
            *(u64*)&hTio[(size_t)(n0 + nl) * 384 + mcb] = pk.w;
        }
#pragma unroll
        for (int r = 0; r < 4; ++r) {
            float s = 0.f, sq = 0.f;
#pragma unroll
            for (int j = 0; j < 4; ++j) {
                const float v = acc[i][j][r] + bi4[r];
                s += v; sq += v * v;
            }
#pragma unroll
            for (int off = 1; off < 16; off <<= 1) {
                s += __shfl_xor(s, off);
                sq += __shfl_xor(sq, off);
            }
            if (l15 == 0) { sds[mcb + r] = s; sds[256 + mcb + r] = sq; }
        }
    }
    __syncthreads();
    if (t < 256) {
        atomicAdd(&sums[t], sds[t]);
        atomicAdd(&sumsq[t], sds[256 + t]);
    }
}

// ---------------- GEMM1: B = relu(bn(h0)) applied at staging; c-major out ------------
#define K1 256
#define BNT(PKV, KB)                                                                     \
    {                                                                                    \
        _Pragma("unroll")                                                                \
        for (int e = 0; e < 8; ++e) {                                                    \
            const int kch = (KB) + kcofs + e;                                            \
            float vv = bf2f(PKV.us[e]) * ssc[kch] + ssh[kch];                            \
            PKV.us[e] = f2bf(fmaxf(vv, 0.f));                                            \
        }                                                                                \
    }
#define G1_STEP(BUF, OTH, KCUR, RAC, RAN, RB0, RB1)                                      \
    {                                                                                    \
        short8 a4[4], b4[4];                                                             \
        _Pragma("unroll")                                                                \
        for (int i = 0; i < 4; ++i) a4[i] = *(short8*)&RAC[i];                           \
        _Pragma("unroll")                                                                \
        for (int j = 0; j < 4; ++j)                                                      \
            b4[j] = *(const short8*)&bT[BUF][(wn + j * 16 + l15) * 32 + (q ^ gsw) * 8];  \
        if ((KCUR) + 32 < K1) {                                                          \
            _Pragma("unroll")                                                            \
            for (int i = 0; i < 4; ++i)                                                  \
                RAN[i] = *(const uint4*)(gA + i * 16 * K1 + (KCUR) + 32);                \
        }                                                                                \
        _Pragma("unroll")                                                                \
        for (int i = 0; i < 4; ++i)                                                      \
            _Pragma("unroll")                                                            \
            for (int j = 0; j < 4; ++j)                                                  \
                acc[i][j] = __builtin_amdgcn_mfma_f32_16x16x32_bf16(a4[i], b4[j], acc[i][j], 0, 0, 0); \
        if ((KCUR) + 32 < K1) {                                                          \
            BNT(RB0, (KCUR) + 32)                                                        \
            BNT(RB1, (KCUR) + 32)                                                        \
            *(uint4*)&bT[OTH][ob0] = RB0.v;                                              \
            *(uint4*)&bT[OTH][ob1] = RB1.v;                                              \
            if ((KCUR) + 96 < K1) {                                                      \
                RB0.v = *(const uint4*)(gB0 + (KCUR) + 96);                              \
                RB1.v = *(const uint4*)(gB1 + (KCUR) + 96);                              \
            }                                                                            \
        }                                                                                \
        __syncthreads();                                                                 \
    }

__global__ __launch_bounds__(256)
void gemm1_kernel(const u16* __restrict__ A, const u16* __restrict__ h0,
                  const float* __restrict__ bias, void* __restrict__ yout,
                  const u32* __restrict__ flag,
                  float* __restrict__ sums, float* __restrict__ sumsq,
                  const float* __restrict__ sum0, const float* __restrict__ sq0,
                  const float* __restrict__ gam0, const float* __restrict__ beta0)
{
    __shared__ __align__(16) u16 bT[2][128 * 32];   // 2 x 8 KB
    __shared__ float sds[512];
    __shared__ float ssc[256], ssh[256];
    const int isbf = (int)flag[0];
    const int t = threadIdx.x;
    const int lane = t & 63;
    const int l15 = lane & 15;
    const int q = lane >> 4;
    const int wid = t >> 6;
    const int n0 = blockIdx.x * 128;
    const int m0 = blockIdx.y * 128;
    const int wm = (wid & 1) * 64;
    const int wn = (wid >> 1) * 64;
    const int wp = wid >> 1;

    {   // per-block BN table from layer-0 stats (identical math to old bn_elem)
        const float invNT = 1.0f / (float)NT_TOTAL;
        const float mean = sum0[t] * invNT;
        const float var = sq0[t] * invNT - mean * mean;
        const float rstd = rsqrtf(var + 1e-5f);
        const float sc = gam0[t] * rstd;
        ssc[t] = sc;
        ssh[t] = beta0[t] - mean * sc;
    }

    f32x4 acc[4][4] = {};

    // B staging: 2 chunks/thread; rows t>>2 and 64+(t>>2), kc = (t&3)*8
    const u16* gB0 = h0 + (size_t)(n0 + (t >> 2)) * 384 + (t & 3) * 8;
    const u16* gB1 = h0 + (size_t)(n0 + 64 + (t >> 2)) * 384 + (t & 3) * 8;
    const int kcofs = (t & 3) * 8;
    const int ob0 = (t >> 2) * 32 + (((t & 3) ^ ((t >> 3) & 3)) * 8);
    const int ob1 = (64 + (t >> 2)) * 32 + (((t & 3) ^ ((t >> 3) & 3)) * 8);
    const u16* gA = A + (size_t)(m0 + wm + l15) * K1 + q * 8;
    const int gsw = (l15 >> 1) & 3;

    union PK { uint4 v; u16 us[8]; };
    uint4 raA[4], raB[4];
    PK rb0A, rb1A, rb0B, rb1B;
    {
        PK r0, r1;
        r0.v = *(const uint4*)gB0;
        r1.v = *(const uint4*)gB1;
#pragma unroll
        for (int i = 0; i < 4; ++i) raA[i] = *(const uint4*)(gA + i * 16 * K1);
        __syncthreads();                 // ssc/ssh visible
        BNT(r0, 0)
        BNT(r1, 0)
        *(uint4*)&bT[0][ob0] = r0.v;
        *(uint4*)&bT[0][ob1] = r1.v;
        rb0A.v = *(const uint4*)(gB0 + 32);
        rb1A.v = *(const uint4*)(gB1 + 32);
        rb0B.v = *(const uint4*)(gB0 + 64);
        rb1B.v = *(const uint4*)(gB1 + 64);
        __syncthreads();
    }

#pragma unroll
    for (int kk = 0; kk < K1; kk += 64) {
        G1_STEP(0, 1, kk, raA, raB, rb0A, rb1A)
        G1_STEP(1, 0, kk + 32, raB, raA, rb0B, rb1B)
    }

    // ---- epilogue: fp32/u16 c-major store + stats (r12 mode-0 path) ----
#pragma unroll
    for (int i = 0; i < 4; ++i) {
        const int mBase = m0 + wm + i * 16 + q * 4;   // D row = q*4+reg
        float bi[4];
#pragma unroll
        for (int r = 0; r < 4; ++r) bi[r] = bias[mBase + r];
#pragma unroll
        for (int j = 0; j < 4; ++j) {
            const int col = n0 + wn + j * 16 + l15;    // D col = lane&15
            const size_t obase = ((size_t)(col >> 14) * 256) * NN + (col & 16383);
#pragma unroll
            for (int r = 0; r < 4; ++r) {
                const float v = acc[i][j][r] + bi[r];
                const size_t oi = obase + (size_t)(mBase + r) * NN;
                if (isbf) ((u16*)yout)[oi] = f2bf(v);
                else      ((float*)yout)[oi] = v;
            }
        }
    }
#pragma unroll
    for (int i = 0; i < 4; ++i) {
        const int mloc = wm + i * 16 + q * 4;
#pragma unroll
        for (int r = 0; r < 4; ++r) {
            const float bi = bias[m0 + mloc + r];
            float s = 0.f, sq = 0.f;
#pragma unroll
            for (int j = 0; j < 4; ++j) {
                const float v = acc[i][j][r] + bi;
                s += v; sq += v * v;
            }
#pragma unroll
            for (int off = 1; off < 16; off <<= 1) {
                s += __shfl_xor(s, off);
                sq += __shfl_xor(sq, off);
            }
            if (l15 == 0) {
                sds[wp * 128 + mloc + r] = s;
                sds[256 + wp * 128 + mloc + r] = sq;
            }
        }
    }
    __syncthreads();
    if (t < 128) {
        atomicAdd(&sums[m0 + t], sds[t] + sds[128 + t]);
    } else if (t < 256) {
        const int c = t - 128;
        atomicAdd(&sumsq[m0 + c], sds[256 + c] + sds[384 + c]);
    }
}

// ---------------- final BN + ReLU, IN-PLACE on d_out ---------------------------------
__global__ __launch_bounds__(256)
void final_kernel(void* __restrict__ y, const float* __restrict__ sums,
                  const float* __restrict__ sumsq, const float* __restrict__ gam,
                  const float* __restrict__ beta, const u32* __restrict__ flag)
{
    const int isbf = (int)flag[0];
    const int gid = blockIdx.x * 256 + threadIdx.x;   // x4 elements
    const int c = (gid >> 12) & 255;
    const float invNT = 1.0f / (float)NT_TOTAL;
    const float mean = sums[c] * invNT;
    const float var = sumsq[c] * invNT - mean * mean;
    const float rstd = rsqrtf(var + 1e-5f);
    const float sc = gam[c] * rstd;
    const float sh = beta[c] - mean * sc;
    const size_t idx4 = (size_t)gid * 4;
    float in4[4];
    if (isbf) {
        union { uint2 v2; u16 us[4]; } iv;
        iv.v2 = *(const uint2*)((const u16*)y + idx4);
#pragma unroll
        for (int e = 0; e < 4; ++e) in4[e] = bf2f(iv.us[e]);
    } else {
        const float4 v = *(const float4*)((const float*)y + idx4);
        in4[0] = v.x; in4[1] = v.y; in4[2] = v.z; in4[3] = v.w;
    }
    float o4[4];
#pragma unroll
    for (int e = 0; e < 4; ++e) {
        float v = in4[e] * sc + sh;
        o4[e] = (v != v) ? 777.0f : fmaxf(v, 0.f);    // NaN canary
    }
    if (isbf) {
        union { uint2 v2; u16 us[4]; } o;
#pragma unroll
        for (int e = 0; e < 4; ++e) o.us[e] = f2bf(o4[e]);
        *(uint2*)((u16*)y + idx4) = o.v2;
    } else {
        float4 o; o.x = o4[0]; o.y = o4[1]; o.z = o4[2]; o.w = o4[3];
        *(float4*)((float*)y + idx4) = o;
    }
}

// kept in case the harness expects this symbol to exist (never launched)
__global__ void pointnet_fp_module_24532853195517_kernel() {}

extern "C" void kernel_launch(void* const* d_in, const int* in_sizes, int n_in,
                              void* d_out, int out_size, void* d_ws, size_t ws_size,
                              hipStream_t stream)
{
    const void* xyz1    = d_in[0];
    const void* xyz2    = d_in[1];
    const void* points1 = d_in[2];
    const void* points2 = d_in[3];
    const void* W0 = d_in[4];  const void* b0 = d_in[5];
    const void* g0 = d_in[6];  const void* bt0 = d_in[7];
    const void* W1 = d_in[8];  const void* b1 = d_in[9];
    const void* g1 = d_in[10]; const void* bt1 = d_in[11];

    // ws layout (total 112,541,696 B)
    char* ws = (char*)d_ws;
    float* stats = (float*)ws;                     //      4,096 B (1024 f)
    u32* flag    = (u32*)(ws + 4096);              //          4 B
    float* pf    = (float*)(ws + 8192);            //      6,144 B (b0,g0,bt0,b1,g1,bt1)
    u16* Wb0     = (u16*)(ws + 16384);             //    196,608 B
    u16* Wb1     = (u16*)(ws + 212992);            //    131,072 B
    u32* idxA    = (u32*)(ws + 344064);            //  1,572,864 B
    float* wA    = (float*)(ws + 1916928);         //  1,572,864 B
    u16* p2T     = (u16*)(ws + 3489792);           //  8,388,608 B
    u16* hT      = (u16*)(ws + 11878400);          // 100,663,296 B (131072 x 384)
    float* sum0 = stats, *sq0 = stats + 256, *sum1 = stats + 512, *sq1 = stats + 768;

    // knn s2q scratch in d_out (dead before gemm1 writes y1)
    float4* s2q = (float4*)((char*)d_out + (8u << 20));

    if (ws_size < (size_t)112541696) {
        sentinel_kernel<<<(out_size + 255) / 256, 256, 0, stream>>>((u16*)d_out, out_size);
        return;
    }

    // always-on mini sentinel: overwritten by gemm1 if the pipeline runs
    sentinel_kernel<<<16, 256, 0, stream>>>((u16*)d_out, 4096);

    detect_kernel<<<1, 256, 0, stream>>>((const u32*)xyz1, flag, stats);
    param_kernel<<<384, 256, 0, stream>>>(W0, b0, g0, bt0, W1, b1, g1, bt1, flag, Wb0, Wb1, pf);
    pack2_kernel<<<64, 256, 0, stream>>>(xyz2, s2q, flag);
    transpose_kernel<<<dim3(32, 4, 8), 256, 0, stream>>>(points2, p2T, 256, 2048, 256, 0, flag);
    transpose_kernel<<<dim3(256, 2, 8), 256, 0, stream>>>(points1, hT, 128, 16384, 384, 256, flag);
    knn_kernel<<<2048, 256, 0, stream>>>(s2q, xyz1, idxA, wA, flag);
    interp_kernel<<<16384, 256, 0, stream>>>(p2T, idxA, wA, hT);
    gemm0_kernel<<<2048, 256, 0, stream>>>(Wb0, hT, pf + 0, sum0, sq0);
    gemm1_kernel<<<dim3(1024, 2), 256, 0, stream>>>(Wb1, hT, pf + 768, d_out, flag,
                                                    sum1, sq1, sum0, sq0, pf + 256, pf + 512);
    final_kernel<<<32768, 256, 0, stream>>>(d_out, sum1, sq1, pf + 1024, pf + 1280, flag);
}

// Round 12
// 501.005 us; speedup vs baseline: 1.0978x; 1.0449x over previous
//
#include <hip/hip_runtime.h>
#include <hip/hip_bf16.h>

// ROUND 14 (4th submit; rounds 9/10 replies broke harness extraction via
// stray backtick fences in prose -- source never reached the compiler):
// m97-structure GEMMs (global_load_lds, dbuf LDS, no reg prefetch)
// + shadow stats (64 slots, contention 2048->32) + bn in-place on hT.
// Rationale: r10-r13 bracketed the reg-staged gemm family at ~95-107us with
// MfmaUtil 6-11%/Occ 20% (nothing busy): VGPR-starved concurrency + same-
// address atomicAdd chains. This round: (1) global_load_lds staging (guide-
// verified +67% lever on this chip; frees staging VGPRs; LINEAR LDS dest as
// required), occupancy -> 3-4 blocks/CU; (2) gemm1 reads RAW B: bn applied
// in-place on hT cols 0..255 by a dedicated elementwise pass (r12-verified
// math); (3) stats to 64 shadow slots in dead p2T region (zeroed after
// interp), collapsed by 1-block reduce kernels. Fragment layout / epilogue
// indexing / MFMA operand order: r13-verbatim (operands bit-identical).
// knn (82us) and all input-side kernels: r13 verbatim.

typedef unsigned int u32;
typedef unsigned short u16;
typedef unsigned long long u64;
typedef __attribute__((ext_vector_type(8))) short short8;   // 8 x bf16 bits
typedef __attribute__((ext_vector_type(4))) float f32x4;

#define NT_TOTAL 131072   // B*N flattened columns
#define NN 16384
#define SS 2048

__device__ __forceinline__ float bf2f(u16 u) {
    union { u32 i; float f; } cv; cv.i = ((u32)u) << 16; return cv.f;
}
__device__ __forceinline__ u16 f2bf(float f) {
    union { float f; u32 i; } cv; cv.f = f;
    const u32 r = (cv.i + 0x7FFFu + ((cv.i >> 16) & 1u)) >> 16;   // RNE
    return (u16)r;
}
// dual-dtype scalar load (isbf wave-uniform)
__device__ __forceinline__ float ldf(const void* p, int i, int isbf) {
    return isbf ? bf2f(((const u16*)p)[i]) : ((const float*)p)[i];
}

// async global->LDS 16B: dest LDS must be wave-uniform base + lane*16 (linear).
// as(1)/as(3) pointers formed via integer reinterpret (as(3) = low 32 bits of
// the generic LDS address on AMDGPU).
__device__ __forceinline__ void gll16(const u16* g, const u16* l)
{
    typedef __attribute__((address_space(1))) const void gv;
    typedef __attribute__((address_space(3))) void sv;
    __builtin_amdgcn_global_load_lds((gv*)(unsigned long long)(const void*)g,
                                     (sv*)(unsigned int)(unsigned long long)(const void*)l,
                                     16, 0, 0);
}

// ---------------- detect dtype + zero stats (1 block, 256 thr) -----------------------
__global__ __launch_bounds__(256)
void detect_kernel(const u32* __restrict__ xyz1w, u32* __restrict__ flag,
                   float* __restrict__ stats)
{
    __shared__ int cnt;
    const int t = threadIdx.x;
    if (t == 0) cnt = 0;
    for (int i = t; i < 1024; i += 256) stats[i] = 0.f;
    __syncthreads();
    if (t < 64) {
        const u32 w = xyz1w[t];
        const int e = (int)((w >> 7) & 0xFF);   // bf16 exponent of LOW u16
        if (e >= 96 && e <= 144) atomicAdd(&cnt, 1);
    }
    __syncthreads();
    if (t == 0) flag[0] = (cnt >= 48) ? 1u : 0u;   // p~1 if packed bf16, p~0.19 if fp32
}

// ---------------- sentinel fill (u16 pattern 0x4496 ~ 1200) --------------------------
__global__ __launch_bounds__(256)
void sentinel_kernel(u16* __restrict__ out, int n)
{
    const int i = blockIdx.x * 256 + threadIdx.x;
    if (i < n) out[i] = 0x4496;
}

// ---------------- convert W -> bf16, params -> fp32 ----------------------------------
__global__ __launch_bounds__(256)
void param_kernel(const void* W0, const void* b0, const void* g0, const void* bt0,
                  const void* W1, const void* b1, const void* g1, const void* bt1,
                  const u32* __restrict__ flag,
                  u16* __restrict__ Wb0, u16* __restrict__ Wb1, float* __restrict__ pf)
{
    const int isbf = (int)flag[0];
    const int i = blockIdx.x * 256 + threadIdx.x;   // up to 98304
    if (i < 98304) Wb0[i] = f2bf(ldf(W0, i, isbf));
    if (i < 65536) Wb1[i] = f2bf(ldf(W1, i, isbf));
    if (i < 1536) {
        const void* srcs[6] = { b0, g0, bt0, b1, g1, bt1 };
        pf[i] = ldf(srcs[i >> 8], i & 255, isbf);
    }
}

// ---------------- pack xyz2 -> float4(x,y,z,|s|^2) -----------------------------------
__global__ __launch_bounds__(256)
void pack2_kernel(const void* __restrict__ xyz2, float4* __restrict__ s2q,
                  const u32* __restrict__ flag)
{
    const int isbf = (int)flag[0];
    const int i = blockIdx.x * 256 + threadIdx.x;   // 8*2048 points
    if (i < 8 * SS) {
        const float x = ldf(xyz2, i * 3 + 0, isbf);
        const float y = ldf(xyz2, i * 3 + 1, isbf);
        const float z = ldf(xyz2, i * 3 + 2, isbf);
        float4 v; v.x = x; v.y = y; v.z = z; v.w = x * x + y * y + z * z;
        s2q[i] = v;
    }
}

// ---------------- zero shadow-stat slots (runs after interp; p2T is dead) ------------
__global__ __launch_bounds__(256)
void zero_kernel(float* __restrict__ a, float* __restrict__ b)
{
    const int i = blockIdx.x * 256 + threadIdx.x;
    if (i < 32768) { a[i] = 0.f; b[i] = 0.f; }
}

// ---------------- collapse 64 shadow slots -> sums/sumsq -----------------------------
__global__ __launch_bounds__(256)
void reduce_kernel(const float* __restrict__ sh, float* __restrict__ outSum,
                   float* __restrict__ outSq)
{
    const int t = threadIdx.x;
    float s = 0.f, q = 0.f;
#pragma unroll 8
    for (int j = 0; j < 64; ++j) {
        s += sh[j * 512 + t];
        q += sh[j * 512 + 256 + t];
    }
    outSum[t] = s;
    outSq[t] = q;
}

// ---------------- transpose (bz,Cc,Np) -> bf16 out[(bz*Np+n)*ldout+coff+c] -----------
__global__ __launch_bounds__(256)
void transpose_kernel(const void* __restrict__ in, u16* __restrict__ out,
                      int Cc, int Np, int ldout, int coff, const u32* __restrict__ flag)
{
    __shared__ u16 tile[64][72];
    const int isbf = (int)flag[0];
    const int t = threadIdx.x;
    const int n0 = blockIdx.x * 64, c0 = blockIdx.y * 64, bz = blockIdx.z;
    const int ch = t & 7, r = t >> 3;     // r: 0..31
#pragma unroll
    for (int p = 0; p < 2; ++p) {
        const int cl = r + p * 32;
        const size_t idx = ((size_t)(bz * Cc + c0 + cl)) * Np + n0 + ch * 8;
        union { uint4 v; u16 us[8]; } pk;
        if (isbf) {
            pk.v = *(const uint4*)((const u16*)in + idx);
        } else {
            const float4 va = *(const float4*)((const float*)in + idx);
            const float4 vb = *(const float4*)((const float*)in + idx + 4);
            pk.us[0] = f2bf(va.x); pk.us[1] = f2bf(va.y);
            pk.us[2] = f2bf(va.z); pk.us[3] = f2bf(va.w);
            pk.us[4] = f2bf(vb.x); pk.us[5] = f2bf(vb.y);
            pk.us[6] = f2bf(vb.z); pk.us[7] = f2bf(vb.w);
        }
        *(uint4*)&tile[cl][ch * 8] = pk.v;
    }
    __syncthreads();
#pragma unroll
    for (int p = 0; p < 2; ++p) {
        const int nl = r + p * 32;
        union { uint4 v; u16 us[8]; } pk;
#pragma unroll
        for (int i = 0; i < 8; ++i) pk.us[i] = tile[ch * 8 + i][nl];
        *(uint4*)&out[((size_t)(bz * Np + n0 + nl)) * ldout + coff + c0 + ch * 8] = pk.v;
    }
}

// ---------------- knn v5: 4-wave split + FORCED-uniform s_load + exact refine --------
__global__ __launch_bounds__(256)
void knn_kernel(const float4* __restrict__ s2q, const void* __restrict__ xyz1,
                u32* __restrict__ idxA, float* __restrict__ wA,
                const u32* __restrict__ flag)
{
    __shared__ float skeys[4][64][5];
    const int isbf = (int)flag[0];
    const int t = threadIdx.x;
    const int lane = t & 63;
    const int wid = __builtin_amdgcn_readfirstlane(t >> 6);   // provably uniform
    const int qg = blockIdx.x * 64 + lane;         // 64 queries per block
    const int b = blockIdx.x >> 8;                 // 256 blocks per batch
    const float qx = ldf(xyz1, qg * 3 + 0, isbf);
    const float qy = ldf(xyz1, qg * 3 + 1, isbf);
    const float qz = ldf(xyz1, qg * 3 + 2, isbf);
    const float qx2 = -2.f * qx, qy2 = -2.f * qy, qz2 = -2.f * qz;
    const float qc = qx * qx + qy * qy + qz * qz;   // |q|^2
    const float4* __restrict__ S = s2q + (size_t)b * SS;

    // sorted top-5 of packed keys: key = (d_bits & ~0x7FF) | s  (fp32 compare)
    float k0 = __builtin_inff(), k1 = k0, k2 = k0, k3 = k0, k4 = k0;
    const int sbase = wid * 512;                    // SGPR
#pragma unroll 8
    for (int it = 0; it < 512; ++it) {
        const int s = sbase + it;
        const float4 v = S[s];                      // uniform -> s_load_dwordx4
        float d = fmaf(v.x, qx2, qc);
        d = fmaf(v.y, qy2, d);
        d = fmaf(v.z, qz2, d);
        d += v.w;                                   // |q|^2 - 2 q.s + |s|^2
        const float k = __uint_as_float((__float_as_uint(d) & 0xFFFFF800u) | (u32)s);
        const float o0 = fminf(k, k0);
        const float o1 = __builtin_amdgcn_fmed3f(k, k0, k1);
        const float o2 = __builtin_amdgcn_fmed3f(k, k1, k2);
        const float o3 = __builtin_amdgcn_fmed3f(k, k2, k3);
        const float o4 = __builtin_amdgcn_fmed3f(k, k3, k4);
        k0 = o0; k1 = o1; k2 = o2; k3 = o3; k4 = o4;
    }
    skeys[wid][lane][0] = k0;
    skeys[wid][lane][1] = k1;
    skeys[wid][lane][2] = k2;
    skeys[wid][lane][3] = k3;
    skeys[wid][lane][4] = k4;
    __syncthreads();
    if (wid != 0) return;

    // exact refine: recompute subtract-form distances for the 20 survivors,
    // select top-3 on u64 key (d_bits<<11 | idx) -> exact values + tie->low idx
    u64 e0 = ~0ull, e1 = ~0ull, e2 = ~0ull;
#pragma unroll
    for (int w = 0; w < 4; ++w)
#pragma unroll
        for (int i = 0; i < 5; ++i) {
            const u32 idx = __float_as_uint(skeys[w][lane][i]) & 0x7FFu;
            const float4 c = S[idx];                 // per-lane gather (L1/L2 hit)
            const float dx = qx - c.x, dy = qy - c.y, dz = qz - c.z;
            const float d = fmaf(dz, dz, fmaf(dy, dy, dx * dx));   // exact, >= 0
            const u64 e = ((u64)__float_as_uint(d) << 11) | (u64)idx;
            const bool c0 = e < e0, c1 = e < e1, c2 = e < e2;
            e2 = c1 ? e1 : (c2 ? e : e2);
            e1 = c0 ? e0 : (c1 ? e : e1);
            e0 = c0 ? e : e0;
        }
    const u32 i0 = (u32)(e0 & 0x7FF), i1 = (u32)(e1 & 0x7FF), i2 = (u32)(e2 & 0x7FF);
    const float d0 = fmaxf(__uint_as_float((u32)(e0 >> 11)), 1e-10f);
    const float d1 = fmaxf(__uint_as_float((u32)(e1 >> 11)), 1e-10f);
    const float d2 = fmaxf(__uint_as_float((u32)(e2 >> 11)), 1e-10f);
    const float w0 = 1.f / d0, w1 = 1.f / d1, w2 = 1.f / d2;
    const float inv = 1.f / (w0 + w1 + w2);
    idxA[qg * 3 + 0] = i0; idxA[qg * 3 + 1] = i1; idxA[qg * 3 + 2] = i2;
    wA[qg * 3 + 0] = w0 * inv; wA[qg * 3 + 1] = w1 * inv; wA[qg * 3 + 2] = w2 * inv;
}

// ---------------- interp: hT[n][0..255] = sum_k w_k * p2T[b][idx_k][c] (bf16) --------
__global__ __launch_bounds__(256)
void interp_kernel(const u16* __restrict__ p2T, const u32* __restrict__ idxA,
                   const float* __restrict__ wA, u16* __restrict__ hT)
{
    const int t = threadIdx.x;
    const int pl = t >> 5, g = t & 31;           // 8 points/block, 32 lanes/point
    const int qg = blockIdx.x * 8 + pl;
    const int b = qg >> 14;
    float acc[8] = {0.f, 0.f, 0.f, 0.f, 0.f, 0.f, 0.f, 0.f};
#pragma unroll
    for (int k = 0; k < 3; ++k) {
        const u32 idx = idxA[qg * 3 + k];
        const float w = wA[qg * 3 + k];
        union { uint4 v; u16 us[8]; } pk;
        pk.v = *(const uint4*)(p2T + ((size_t)(b * SS + idx)) * 256 + g * 8);
#pragma unroll
        for (int e = 0; e < 8; ++e) acc[e] = fmaf(w, bf2f(pk.us[e]), acc[e]);
    }
    union { uint4 v; u16 us[8]; } ov;
#pragma unroll
    for (int e = 0; e < 8; ++e) ov.us[e] = f2bf(acc[e]);
    *(uint4*)&hT[(size_t)qg * 384 + g * 8] = ov.v;
}

// ---------------- GEMM0 (m97-style): 64 cols x 256 ch per block ----------------------
// global_load_lds dbuf staging; h0 = f2bf(y0) written IN-PLACE into hT cols
// 0..255 (block-exclusive rows); stats to shadow slot (blockIdx.x & 63).
#define K0 384
__global__ __launch_bounds__(256)
void gemm0_kernel(const u16* __restrict__ A, u16* __restrict__ hTio,
                  const float* __restrict__ bias, float* __restrict__ sh0)
{
    __shared__ __align__(16) u16 aB[2][256 * 32];   // 2 x 16 KB
    __shared__ __align__(16) u16 bB[2][64 * 32];    // 2 x 4 KB
    __shared__ float sds[512];
    const int t = threadIdx.x;
    const int lane = t & 63;
    const int l15 = lane & 15;
    const int q = lane >> 4;
    const int wid = t >> 6;
    const int n0 = blockIdx.x * 64;
    const int wm = wid * 64;                        // wave-exclusive channel slice

    f32x4 acc[4][4] = {};

    // thread chunk: B row t>>2 (0..63), A rows p*64 + (t>>2); k-chunk (t&3)*8
    const u16* gB = hTio + (size_t)(n0 + (t >> 2)) * 384 + (t & 3) * 8;
    const u16* gA = A + (size_t)(t >> 2) * K0 + (t & 3) * 8;

    // prologue: tile 0 -> buf 0
    gll16(gB, &bB[0][t * 8]);
#pragma unroll
    for (int p = 0; p < 4; ++p)
        gll16(gA + (size_t)p * 64 * K0, &aB[0][(p * 256 + t) * 8]);
    __syncthreads();

#pragma unroll
    for (int kk = 0; kk < K0; kk += 32) {
        const int cur = (kk >> 5) & 1;
        if (kk + 32 < K0) {
            gll16(gB + kk + 32, &bB[cur ^ 1][t * 8]);
#pragma unroll
            for (int p = 0; p < 4; ++p)
                gll16(gA + (size_t)p * 64 * K0 + kk + 32, &aB[cur ^ 1][(p * 256 + t) * 8]);
        }
        short8 a4[4], b4[4];
#pragma unroll
        for (int i = 0; i < 4; ++i)
            a4[i] = *(const short8*)&aB[cur][(wm + i * 16 + l15) * 32 + q * 8];
#pragma unroll
        for (int j = 0; j < 4; ++j)
            b4[j] = *(const short8*)&bB[cur][(j * 16 + l15) * 32 + q * 8];
#pragma unroll
        for (int i = 0; i < 4; ++i)
#pragma unroll
            for (int j = 0; j < 4; ++j)
                acc[i][j] = __builtin_amdgcn_mfma_f32_16x16x32_bf16(a4[i], b4[j], acc[i][j], 0, 0, 0);
        __syncthreads();
    }

    // epilogue: h0 in-place stores (all reads drained at last barrier) + stats
#pragma unroll
    for (int i = 0; i < 4; ++i) {
        const int mcb = wm + i * 16 + q * 4;
        float bi4[4];
#pragma unroll
        for (int r = 0; r < 4; ++r) bi4[r] = bias[mcb + r];
#pragma unroll
        for (int j = 0; j < 4; ++j) {
            const int nl = j * 16 + l15;
            union { u64 w; u16 us[4]; } pk;
#pragma unroll
            for (int r = 0; r < 4; ++r) pk.us[r] = f2bf(acc[i][j][r] + bi4[r]);
            *(u64*)&hTio[(size_t)(n0 + nl) * 384 + mcb] = pk.w;
        }
#pragma unroll
        for (int r = 0; r < 4; ++r) {
            float s = 0.f, sq = 0.f;
#pragma unroll
            for (int j = 0; j < 4; ++j) {
                const float v = acc[i][j][r] + bi4[r];
                s += v; sq += v * v;
            }
#pragma unroll
            for (int off = 1; off < 16; off <<= 1) {
                s += __shfl_xor(s, off);
                sq += __shfl_xor(sq, off);
            }
            if (l15 == 0) { sds[mcb + r] = s; sds[256 + mcb + r] = sq; }
        }
    }
    __syncthreads();
    const int jsh = blockIdx.x & 63;
    atomicAdd(&sh0[jsh * 512 + t], sds[t]);
    atomicAdd(&sh0[jsh * 512 + 256 + t], sds[256 + t]);
}

// ---------------- BN + ReLU IN-PLACE on hT cols 0..255 -------------------------------
__global__ __launch_bounds__(256)
void bn_kernel(u16* __restrict__ hT, const float* __restrict__ sums,
               const float* __restrict__ sumsq, const float* __restrict__ gam,
               const float* __restrict__ beta)
{
    __shared__ float ssc[256], ssh[256];
    const int t = threadIdx.x;
    {
        const float invNT = 1.0f / (float)NT_TOTAL;
        const float mean = sums[t] * invNT;
        const float var = sumsq[t] * invNT - mean * mean;
        const float rstd = rsqrtf(var + 1e-5f);
        const float sc = gam[t] * rstd;
        ssc[t] = sc;
        ssh[t] = beta[t] - mean * sc;
    }
    __syncthreads();
    const int row = blockIdx.x * 8 + (t >> 5);      // 131072 rows / 8 = 16384 blocks
    const int cb = (t & 31) * 8;
    u16* p = hT + (size_t)row * 384 + cb;
    union { uint4 v; u16 us[8]; } pk;
    pk.v = *(const uint4*)p;
#pragma unroll
    for (int e = 0; e < 8; ++e) {
        float v = bf2f(pk.us[e]) * ssc[cb + e] + ssh[cb + e];
        v = (v != v) ? 777.0f : fmaxf(v, 0.f);      // NaN canary
        pk.us[e] = f2bf(v);
    }
    *(uint4*)p = pk.v;
}

// ---------------- GEMM1 (m97-style): raw B = h2-in-hT; c-major out -------------------
#define K1 256
__global__ __launch_bounds__(256)
void gemm1_kernel(const u16* __restrict__ A, const u16* __restrict__ h2,
                  const float* __restrict__ bias, void* __restrict__ yout,
                  const u32* __restrict__ flag, float* __restrict__ sh1)
{
    __shared__ __align__(16) u16 aB[2][128 * 32];   // 2 x 8 KB
    __shared__ __align__(16) u16 bB[2][128 * 32];   // 2 x 8 KB
    __shared__ float sds[512];
    const int isbf = (int)flag[0];
    const int t = threadIdx.x;
    const int lane = t & 63;
    const int l15 = lane & 15;
    const int q = lane >> 4;
    const int wid = t >> 6;
    const int n0 = blockIdx.x * 128;
    const int m0 = blockIdx.y * 128;
    const int wm = (wid & 1) * 64;
    const int wn = (wid >> 1) * 64;
    const int wp = wid >> 1;

    f32x4 acc[4][4] = {};

    // thread chunks: rows t>>2 and 64+(t>>2); k-chunk (t&3)*8
    const u16* gB0 = h2 + (size_t)(n0 + (t >> 2)) * 384 + (t & 3) * 8;
    const u16* gB1 = gB0 + (size_t)64 * 384;
    const u16* gA0 = A + (size_t)(m0 + (t >> 2)) * K1 + (t & 3) * 8;
    const u16* gA1 = gA0 + (size_t)64 * K1;

    // prologue: tile 0 -> buf 0
    gll16(gA0, &aB[0][t * 8]);
    gll16(gA1, &aB[0][(256 + t) * 8]);
    gll16(gB0, &bB[0][t * 8]);
    gll16(gB1, &bB[0][(256 + t) * 8]);
    __syncthreads();

#pragma unroll
    for (int kk = 0; kk < K1; kk += 32) {
        const int cur = (kk >> 5) & 1;
        if (kk + 32 < K1) {
            gll16(gA0 + kk + 32, &aB[cur ^ 1][t * 8]);
            gll16(gA1 + kk + 32, &aB[cur ^ 1][(256 + t) * 8]);
            gll16(gB0 + kk + 32, &bB[cur ^ 1][t * 8]);
            gll16(gB1 + kk + 32, &bB[cur ^ 1][(256 + t) * 8]);
        }
        short8 a4[4], b4[4];
#pragma unroll
        for (int i = 0; i < 4; ++i)
            a4[i] = *(const short8*)&aB[cur][(wm + i * 16 + l15) * 32 + q * 8];
#pragma unroll
        for (int j = 0; j < 4; ++j)
            b4[j] = *(const short8*)&bB[cur][(wn + j * 16 + l15) * 32 + q * 8];
#pragma unroll
        for (int i = 0; i < 4; ++i)
#pragma unroll
            for (int j = 0; j < 4; ++j)
                acc[i][j] = __builtin_amdgcn_mfma_f32_16x16x32_bf16(a4[i], b4[j], acc[i][j], 0, 0, 0);
        __syncthreads();
    }

    // ---- epilogue: fp32/u16 c-major store + shadow stats ----
#pragma unroll
    for (int i = 0; i < 4; ++i) {
        const int mBase = m0 + wm + i * 16 + q * 4;   // D row = q*4+reg
        float bi[4];
#pragma unroll
        for (int r = 0; r < 4; ++r) bi[r] = bias[mBase + r];
#pragma unroll
        for (int j = 0; j < 4; ++j) {
            const int col = n0 + wn + j * 16 + l15;    // D col = lane&15
            const size_t obase = ((size_t)(col >> 14) * 256) * NN + (col & 16383);
#pragma unroll
            for (int r = 0; r < 4; ++r) {
                const float v = acc[i][j][r] + bi[r];
                const size_t oi = obase + (size_t)(mBase + r) * NN;
                if (isbf) ((u16*)yout)[oi] = f2bf(v);
                else      ((float*)yout)[oi] = v;
            }
        }
    }
#pragma unroll
    for (int i = 0; i < 4; ++i) {
        const int mloc = wm + i * 16 + q * 4;
#pragma unroll
        for (int r = 0; r < 4; ++r) {
            const float bi = bias[m0 + mloc + r];
            float s = 0.f, sq = 0.f;
#pragma unroll
            for (int j = 0; j < 4; ++j) {
                const float v = acc[i][j][r] + bi;
                s += v; sq += v * v;
            }
#pragma unroll
            for (int off = 1; off < 16; off <<= 1) {
                s += __shfl_xor(s, off);
                sq += __shfl_xor(sq, off);
            }
            if (l15 == 0) {
                sds[wp * 128 + mloc + r] = s;
                sds[256 + wp * 128 + mloc + r] = sq;
            }
        }
    }
    __syncthreads();
    const int jsh = blockIdx.x & 63;
    if (t < 128) {
        atomicAdd(&sh1[jsh * 512 + m0 + t], sds[t] + sds[128 + t]);
    } else if (t < 256) {
        const int c = t - 128;
        atomicAdd(&sh1[jsh * 512 + 256 + m0 + c], sds[256 + c] + sds[384 + c]);
    }
}

// ---------------- final BN + ReLU, IN-PLACE on d_out ---------------------------------
__global__ __launch_bounds__(256)
void final_kernel(void* __restrict__ y, const float* __restrict__ sums,
                  const float* __restrict__ sumsq, const float* __restrict__ gam,
                  const float* __restrict__ beta, const u32* __restrict__ flag)
{
    const int isbf = (int)flag[0];
    const int gid = blockIdx.x * 256 + threadIdx.x;   // x4 elements
    const int c = (gid >> 12) & 255;
    const float invNT = 1.0f / (float)NT_TOTAL;
    const float mean = sums[c] * invNT;
    const float var = sumsq[c] * invNT - mean * mean;
    const float rstd = rsqrtf(var + 1e-5f);
    const float sc = gam[c] * rstd;
    const float sh = beta[c] - mean * sc;
    const size_t idx4 = (size_t)gid * 4;
    float in4[4];
    if (isbf) {
        union { uint2 v2; u16 us[4]; } iv;
        iv.v2 = *(const uint2*)((const u16*)y + idx4);
#pragma unroll
        for (int e = 0; e < 4; ++e) in4[e] = bf2f(iv.us[e]);
    } else {
        const float4 v = *(const float4*)((const float*)y + idx4);
        in4[0] = v.x; in4[1] = v.y; in4[2] = v.z; in4[3] = v.w;
    }
    float o4[4];
#pragma unroll
    for (int e = 0; e < 4; ++e) {
        float v = in4[e] * sc + sh;
        o4[e] = (v != v) ? 777.0f : fmaxf(v, 0.f);    // NaN canary
    }
    if (isbf) {
        union { uint2 v2; u16 us[4]; } o;
#pragma unroll
        for (int e = 0; e < 4; ++e) o.us[e] = f2bf(o4[e]);
        *(uint2*)((u16*)y + idx4) = o.v2;
    } else {
        float4 o; o.x = o4[0]; o.y = o4[1]; o.z = o4[2]; o.w = o4[3];
        *(float4*)((float*)y + idx4) = o;
    }
}

// kept in case the harness expects this symbol to exist (never launched)
__global__ void pointnet_fp_module_24532853195517_kernel() {}

extern "C" void kernel_launch(void* const* d_in, const int* in_sizes, int n_in,
                              void* d_out, int out_size, void* d_ws, size_t ws_size,
                              hipStream_t stream)
{
    const void* xyz1    = d_in[0];
    const void* xyz2    = d_in[1];
    const void* points1 = d_in[2];
    const void* points2 = d_in[3];
    const void* W0 = d_in[4];  const void* b0 = d_in[5];
    const void* g0 = d_in[6];  const void* bt0 = d_in[7];
    const void* W1 = d_in[8];  const void* b1 = d_in[9];
    const void* g1 = d_in[10]; const void* bt1 = d_in[11];

    // ws layout (total 112,541,696 B)
    char* ws = (char*)d_ws;
    float* stats = (float*)ws;                     //      4,096 B (1024 f)
    u32* flag    = (u32*)(ws + 4096);              //          4 B
    float* pf    = (float*)(ws + 8192);            //      6,144 B (b0,g0,bt0,b1,g1,bt1)
    u16* Wb0     = (u16*)(ws + 16384);             //    196,608 B
    u16* Wb1     = (u16*)(ws + 212992);            //    131,072 B
    u32* idxA    = (u32*)(ws + 344064);            //  1,572,864 B
    float* wA    = (float*)(ws + 1916928);         //  1,572,864 B
    u16* p2T     = (u16*)(ws + 3489792);           //  8,388,608 B (dead after interp)
    u16* hT      = (u16*)(ws + 11878400);          // 100,663,296 B (131072 x 384)
    float* sum0 = stats, *sq0 = stats + 256, *sum1 = stats + 512, *sq1 = stats + 768;

    // shadow stat slots live in the dead p2T region (zeroed after interp)
    float* sh0 = (float*)p2T;                      // 64 x 512 f = 128 KB
    float* sh1 = sh0 + 32768;                      // 64 x 512 f = 128 KB

    // knn s2q scratch in d_out (dead before gemm1 writes y1)
    float4* s2q = (float4*)((char*)d_out + (8u << 20));

    if (ws_size < (size_t)112541696) {
        sentinel_kernel<<<(out_size + 255) / 256, 256, 0, stream>>>((u16*)d_out, out_size);
        return;
    }

    // always-on mini sentinel: overwritten by gemm1 if the pipeline runs
    sentinel_kernel<<<16, 256, 0, stream>>>((u16*)d_out, 4096);

    detect_kernel<<<1, 256, 0, stream>>>((const u32*)xyz1, flag, stats);
    param_kernel<<<384, 256, 0, stream>>>(W0, b0, g0, bt0, W1, b1, g1, bt1, flag, Wb0, Wb1, pf);
    pack2_kernel<<<64, 256, 0, stream>>>(xyz2, s2q, flag);
    transpose_kernel<<<dim3(32, 4, 8), 256, 0, stream>>>(points2, p2T, 256, 2048, 256, 0, flag);
    transpose_kernel<<<dim3(256, 2, 8), 256, 0, stream>>>(points1, hT, 128, 16384, 384, 256, flag);
    knn_kernel<<<2048, 256, 0, stream>>>(s2q, xyz1, idxA, wA, flag);
    interp_kernel<<<16384, 256, 0, stream>>>(p2T, idxA, wA, hT);
    zero_kernel<<<128, 256, 0, stream>>>(sh0, sh1);
    gemm0_kernel<<<2048, 256, 0, stream>>>(Wb0, hT, pf + 0, sh0);
    reduce_kernel<<<1, 256, 0, stream>>>(sh0, sum0, sq0);
    bn_kernel<<<16384, 256, 0, stream>>>(hT, sum0, sq0, pf + 256, pf + 512);
    gemm1_kernel<<<dim3(1024, 2), 256, 0, stream>>>(Wb1, hT, pf + 768, d_out, flag, sh1);
    reduce_kernel<<<1, 256, 0, stream>>>(sh1, sum1, sq1);
    final_kernel<<<32768, 256, 0, stream>>>(d_out, sum1, sq1, pf + 1024, pf + 1280, flag);
}